// Round 3
// baseline (216.529 us; speedup 1.0000x reference)
//
#include <hip/hip_runtime.h>
#include <math.h>

// Problem constants (from reference setup_inputs)
#define BBATCH 16
#define NPTS   4096
#define MPTS   1024
#define C1c    128
#define C2c    256
#define CINc   384
#define H1c    256
#define H2c    128
#define TN     64

typedef _Float16 f16x8 __attribute__((ext_vector_type(8)));
typedef _Float16 f16x4 __attribute__((ext_vector_type(4)));
typedef float    f32x4 __attribute__((ext_vector_type(4)));

// ---- LDS layout (bytes) ---------------------------------------------------
// union [0,49152):
//   phase A: inv dbuf 2 x [4 cc][4 nt][64 lane][8 f16] = 32768 B
//   phase B: s_X frags [12 kc][4 nt][64][8] f16 = 49152 B
//   phase C: s_H frags [8 oc][4 nt][64][8] f16 = 32768 B
// s_xyz2 [1024][3] f32 = 12288 B at 49152  (OUTSIDE the union: survives both
//   tiles of the block — R9 overlaid it and a 2-tile block would lose it)
// s_red 256 f32 at 61440
// Total 62464 B -> 2 blocks/CU (125 KB), matching the 512-block balanced grid.
#define INV_HALF   8192            // f16 elems per inv buffer (16384 B)
#define OFF_XYZ2   49152
#define OFF_RED    61440
#define SMEM_BYTES 62464

// ---- fragment-swizzled workspace layout (f16 elements), unchanged ----
//   p2s: frag ((b*32+s)*16 + wt)*64 + lane : (c=wt*16+(lane&15), m=s*32+(lane>>4)*8+i)
//   W1s: frag (wt*12 + kc)*64 + lane       : (o=wt*16+(lane&15), k=kc*32+(lane>>4)*8+i)
//   W2s: frag (wt2*8 + oc)*64 + lane       : (o=wt2*16+(lane&15), k=oc*32+(lane>>4)*8+i)
#define NFRAG_P2  (BBATCH * 32 * 16 * 64)        // 524288
#define NFRAG_W1  (16 * 12 * 64)                 // 12288
#define NFRAG_W2  (8 * 8 * 64)                   // 4096
#define WS_P2S  0
#define WS_W1S  (NFRAG_P2 * 8)                   // 4194304
#define WS_W2S  (WS_W1S + NFRAG_W1 * 8)
#define WS_F16_TOTAL (WS_W2S + NFRAG_W2 * 8)     // 4325376 f16 = 8650752 B

// ---------------------------------------------------------------------------
// pre-pass: convert + swizzle p2 / W1 / W2 into fragment-contiguous f16
__global__ __launch_bounds__(256) void cvt_swz(
    const float* __restrict__ p2, const float* __restrict__ W1,
    const float* __restrict__ W2, _Float16* __restrict__ ws)
{
    const int t = blockIdx.x * 256 + threadIdx.x;   // one fragment (8 f16) per thread
    const float* src;
    _Float16* dst;
    if (t < NFRAG_P2) {
        const int lane = t & 63, wt = (t >> 6) & 15, s = (t >> 10) & 31, b = t >> 15;
        const int c = wt * 16 + (lane & 15);
        const int m = s * 32 + (lane >> 4) * 8;
        src = p2 + ((size_t)(b * C2c + c)) * MPTS + m;
        dst = ws + WS_P2S + (size_t)t * 8;
    } else if (t < NFRAG_P2 + NFRAG_W1) {
        const int u = t - NFRAG_P2;
        const int lane = u & 63, kc = (u >> 6) % 12, wt = (u >> 6) / 12;
        const int o = wt * 16 + (lane & 15);
        const int k = kc * 32 + (lane >> 4) * 8;
        src = W1 + (size_t)o * CINc + k;
        dst = ws + WS_W1S + (size_t)u * 8;
    } else {
        const int v = t - NFRAG_P2 - NFRAG_W1;
        const int lane = v & 63, oc = (v >> 6) & 7, wt2 = v >> 9;
        const int o = wt2 * 16 + (lane & 15);
        const int k = oc * 32 + (lane >> 4) * 8;
        src = W2 + (size_t)o * H1c + k;
        dst = ws + WS_W2S + (size_t)v * 8;
    }
    const float4 a0 = *(const float4*)(src);
    const float4 a1 = *(const float4*)(src + 4);
    f16x8 h;
    h[0] = (_Float16)a0.x; h[1] = (_Float16)a0.y; h[2] = (_Float16)a0.z; h[3] = (_Float16)a0.w;
    h[4] = (_Float16)a1.x; h[5] = (_Float16)a1.y; h[6] = (_Float16)a1.z; h[7] = (_Float16)a1.w;
    *(f16x8*)dst = h;
}

// ---------------------------------------------------------------------------
// R10: balanced persistent schedule + deeper prefetch.
//  - 512 blocks x 2 n-tiles each = exactly 2 blocks/CU: removes R9's 4th-round
//    occupancy tail (grid 1024 @ 3/CU residency). xyz2 staged once per block.
//  - __launch_bounds__(256,2): 256-reg budget (2 waves/SIMD is the residency
//    anyway) -> room for ring-4 A-frag buffer, prefetch distance 2 (~156 cyc
//    of MFMA cover vs ~200 cyc L2 latency; R9's distance-1 was ~78 cyc).
//  - gen() split per-cc: inv VALU work interleaves with each MFMA cluster.
//  - phases B/C: explicit ping-pong prefetch of W frags (full unroll, static).
template <bool F16P>
__global__ __launch_bounds__(256, 2) void fp_mfma10(
    const float* __restrict__ xyz1, const float* __restrict__ xyz2,
    const float* __restrict__ p1,   const float* __restrict__ p2,
    const float* __restrict__ W1,   const float* __restrict__ b1v,
    const float* __restrict__ W2,   const float* __restrict__ b2v,
    const _Float16* __restrict__ p2s, const _Float16* __restrict__ W1s,
    const _Float16* __restrict__ W2s,
    float* __restrict__ out)
{
    __shared__ __align__(16) char smem[SMEM_BYTES];
    _Float16* s_inv  = (_Float16*)smem;
    _Float16* s_X    = (_Float16*)smem;
    _Float16* s_H    = (_Float16*)smem;
    float*    s_xyz2 = (float*)(smem + OFF_XYZ2);
    float*    s_red  = (float*)(smem + OFF_RED);

    const int tid  = threadIdx.x;
    const int w    = tid >> 6;    // wave 0..3
    const int L    = tid & 63;
    const int quad = L >> 4;
    const int l16  = L & 15;

    // XCD swizzle: each XCD sees 2 batches -> p2s working set (1 MB) L2-resident
    const int id = blockIdx.x;            // 512 blocks
    const int b  = (id & 7) * 2 + ((id >> 3) & 1);
    const int n0base = (id >> 4) * (2 * TN);   // this block owns tiles n0base, n0base+64

    const float* __restrict__ z2b = xyz2 + (size_t)b * MPTS * 3;
    const float* __restrict__ p2b = p2   + (size_t)b * C2c * MPTS;
    const _Float16* __restrict__ p2sb =
        F16P ? (p2s + (((size_t)b * 32 * 16 + (size_t)w * 4) * 64 + L) * 8) : (const _Float16*)nullptr;

    // stage xyz2 once per block (survives both tiles: lives outside the union)
    for (int i = tid; i < MPTS * 3 / 4; i += 256)
        ((f32x4*)s_xyz2)[i] = ((const f32x4*)z2b)[i];

    auto loadA = [&](int s, f16x8 dst[4]) {
        if (F16P) {
            const _Float16* ap = p2sb + (size_t)s * (16 * 64 * 8);
            #pragma unroll
            for (int ct = 0; ct < 4; ++ct)
                dst[ct] = *(const f16x8*)(ap + (size_t)ct * (64 * 8));
        } else {
            const float* ap = p2b + (size_t)(w * 64 + l16) * MPTS + s * 32 + quad * 8;
            #pragma unroll
            for (int ct = 0; ct < 4; ++ct) {
                const float4 a0 = *(const float4*)(ap + (size_t)ct * (16 * MPTS));
                const float4 a1 = *(const float4*)(ap + (size_t)ct * (16 * MPTS) + 4);
                f16x8 h;
                h[0] = (_Float16)a0.x; h[1] = (_Float16)a0.y; h[2] = (_Float16)a0.z; h[3] = (_Float16)a0.w;
                h[4] = (_Float16)a1.x; h[5] = (_Float16)a1.y; h[6] = (_Float16)a1.z; h[7] = (_Float16)a1.w;
                dst[ct] = h;
            }
        }
    };

    auto loadW1 = [&](int kc, f16x8 dst[4]) {
        if (F16P) {
            const _Float16* wp = W1s + (((size_t)(w * 4) * 12 + kc) * 64 + L) * 8;
            #pragma unroll
            for (int ct = 0; ct < 4; ++ct)
                dst[ct] = *(const f16x8*)(wp + (size_t)ct * (12 * 64 * 8));
        } else {
            const float* wp = W1 + (size_t)(w * 64 + l16) * CINc + kc * 32 + quad * 8;
            #pragma unroll
            for (int ct = 0; ct < 4; ++ct) {
                const float4 a0 = *(const float4*)(wp + ct * (16 * CINc));
                const float4 a1 = *(const float4*)(wp + ct * (16 * CINc) + 4);
                f16x8 h;
                h[0] = (_Float16)a0.x; h[1] = (_Float16)a0.y; h[2] = (_Float16)a0.z; h[3] = (_Float16)a0.w;
                h[4] = (_Float16)a1.x; h[5] = (_Float16)a1.y; h[6] = (_Float16)a1.z; h[7] = (_Float16)a1.w;
                dst[ct] = h;
            }
        }
    };

    auto loadW2 = [&](int oc, f16x8 dst[2]) {
        if (F16P) {
            const _Float16* wp = W2s + (((size_t)(w * 2) * 8 + oc) * 64 + L) * 8;
            #pragma unroll
            for (int ct = 0; ct < 2; ++ct)
                dst[ct] = *(const f16x8*)(wp + (size_t)ct * (8 * 64 * 8));
        } else {
            const float* wp = W2 + (size_t)(w * 32 + l16) * H1c + oc * 32 + quad * 8;
            #pragma unroll
            for (int ct = 0; ct < 2; ++ct) {
                const float4 a0 = *(const float4*)(wp + ct * (16 * H1c));
                const float4 a1 = *(const float4*)(wp + ct * (16 * H1c) + 4);
                f16x8 h;
                h[0] = (_Float16)a0.x; h[1] = (_Float16)a0.y; h[2] = (_Float16)a0.z; h[3] = (_Float16)a0.w;
                h[4] = (_Float16)a1.x; h[5] = (_Float16)a1.y; h[6] = (_Float16)a1.z; h[7] = (_Float16)a1.w;
                dst[ct] = h;
            }
        }
    };

    for (int t = 0; t < 2; ++t) {
        const int n0 = n0base + t * TN;

        const float x1x = xyz1[((size_t)b * NPTS + n0 + L) * 3 + 0];
        const float x1y = xyz1[((size_t)b * NPTS + n0 + L) * 3 + 1];
        const float x1z = xyz1[((size_t)b * NPTS + n0 + L) * 3 + 2];

        f32x4 acc[4][4];   // [ct][nt]: row c = w*64+ct*16+quad*4+r, col n = nt*16+l16
        #pragma unroll
        for (int ct = 0; ct < 4; ++ct)
            #pragma unroll
            for (int nt = 0; nt < 4; ++nt)
                acc[ct][nt] = (f32x4){0.f, 0.f, 0.f, 0.f};

        float ssum = 0.f;
        f16x8 Aa[4][4];    // A-frag ring, slot = s & 3 (prefetch distance 2)

        // one 8-m group of super-chunk ss_ into frag-layout buffer (ss_&1):
        // thread (w,L): n=L, m = ss_*128 + w*32 + g*8 + i -> frag (cc=w, nt=quad),
        // lane slot l' = 16*g + l16. One dense f16x8 store.
        auto gen_g = [&](int ss_, int g) {
            _Float16* buf = s_inv + (ss_ & 1) * INV_HALF;
            const float* zp = s_xyz2 + (size_t)(ss_ * 128 + w * 32 + g * 8) * 3;
            f32x4 zr[6];
            #pragma unroll
            for (int j = 0; j < 6; ++j) zr[j] = ((const f32x4*)zp)[j];
            const float* zv = (const float*)zr;
            f16x8 iv;
            #pragma unroll
            for (int i = 0; i < 8; ++i) {
                const float dx = x1x - zv[3 * i + 0];
                const float dy = x1y - zv[3 * i + 1];
                const float dz = x1z - zv[3 * i + 2];
                const float d2 = fmaf(dx, dx, fmaf(dy, dy, fmaf(dz, dz, 1e-12f)));
                const float inv = __builtin_amdgcn_rsqf(d2);
                ssum += inv;
                iv[i] = (_Float16)inv;
            }
            *(f16x8*)(buf + (((w * 4 + quad) * 64) + g * 16 + l16) * 8) = iv;
        };

        loadA(0, Aa[0]);
        loadA(1, Aa[1]);
        __syncthreads();   // t=0: xyz2 staged; t=1: phase-C s_H reads done
        #pragma unroll
        for (int g = 0; g < 4; ++g) gen_g(0, g);
        __syncthreads();   // super-chunk 0 visible

        for (int ss = 0; ss < 8; ++ss) {
            const _Float16* buf = s_inv + (ss & 1) * INV_HALF;
            #pragma unroll
            for (int cc = 0; cc < 4; ++cc) {
                const int s = ss * 4 + cc;
                if (s + 2 < 32) loadA(s + 2, Aa[(cc + 2) & 3]);  // distance-2 ring prefetch
                if (ss + 1 < 8) gen_g(ss + 1, cc);               // inv VALU interleaved per step
                __builtin_amdgcn_s_setprio(1);
                #pragma unroll
                for (int nt = 0; nt < 4; ++nt) {
                    const f16x8 bf = *(const f16x8*)(buf + ((cc * 4 + nt) * 64 + L) * 8);
                    #pragma unroll
                    for (int ct = 0; ct < 4; ++ct)
                        acc[ct][nt] = __builtin_amdgcn_mfma_f32_16x16x32_f16(Aa[cc][ct], bf, acc[ct][nt], 0, 0, 0);
                }
                __builtin_amdgcn_s_setprio(0);
            }
            __syncthreads();   // reads of buf(ss) done; writes of buf(ss+1) done
        }

        // p1 -> s_X frags kq=w (bytes [0,16K) = dead inv buf0). Issued BEFORE
        // the reduction so the 32 global loads hide under reduction+interp.
        {
            const float* p1b = p1 + ((size_t)b * C1c + w * 32 + quad * 8) * NPTS + n0 + l16;
            #pragma unroll
            for (int cc = 0; cc < 4; ++cc) {
                float tv[8];
                #pragma unroll
                for (int j = 0; j < 8; ++j) tv[j] = p1b[(size_t)j * NPTS + cc * 16];
                f16x8 v;
                #pragma unroll
                for (int j = 0; j < 8; ++j) v[j] = (_Float16)tv[j];
                *(f16x8*)(s_X + ((w * 4 + cc) * 64 + L) * 8) = v;
            }
        }

        // ---- S[n] reduction; recip overlaid in s_red[0..63]
        s_red[tid] = ssum;
        __syncthreads();
        if (tid < 64)
            s_red[tid] = 1.0f / (s_red[tid] + s_red[tid + 64] + s_red[tid + 128] + s_red[tid + 192]);
        __syncthreads();

        // interp -> s_X frags kq = 4 + 2w + (ct>>1) (bytes [16K,48K): dead buf1
        // + free union space — xyz2 now lives outside the union).
        {
            float rn4[4];
            #pragma unroll
            for (int nt = 0; nt < 4; ++nt) rn4[nt] = s_red[nt * 16 + l16];
            #pragma unroll
            for (int ct = 0; ct < 4; ++ct) {
                const int kq = 4 + 2 * w + (ct >> 1);
                const int lp = l16 + 16 * (((ct & 1) * 2) + (quad >> 1));
                const int jo = (quad & 1) * 4;
                #pragma unroll
                for (int nt = 0; nt < 4; ++nt) {
                    const f32x4 v = acc[ct][nt];
                    const float r = rn4[nt];
                    f16x4 hv;
                    hv[0] = (_Float16)(v[0] * r);
                    hv[1] = (_Float16)(v[1] * r);
                    hv[2] = (_Float16)(v[2] * r);
                    hv[3] = (_Float16)(v[3] * r);
                    *(f16x4*)(s_X + ((kq * 4 + nt) * 64 + lp) * 8 + jo) = hv;
                }
            }
        }
        __syncthreads();   // full X (p1 + interp) frags complete

        // ---------------- Phase B: h = relu(W1 @ X + b1), K=384 ------------
        f32x4 hacc[4][4];
        #pragma unroll
        for (int ct = 0; ct < 4; ++ct)
            #pragma unroll
            for (int nt = 0; nt < 4; ++nt)
                hacc[ct][nt] = (f32x4){0.f, 0.f, 0.f, 0.f};

        {
            f16x8 afP[2][4];   // ping-pong, static kc&1 indexing (full unroll)
            loadW1(0, afP[0]);
            #pragma unroll
            for (int kc = 0; kc < 12; ++kc) {
                if (kc + 1 < 12) loadW1(kc + 1, afP[(kc + 1) & 1]);
                __builtin_amdgcn_s_setprio(1);
                #pragma unroll
                for (int nt = 0; nt < 4; ++nt) {
                    const f16x8 bf = *(const f16x8*)(s_X + ((kc * 4 + nt) * 64 + L) * 8);
                    #pragma unroll
                    for (int ct = 0; ct < 4; ++ct)
                        hacc[ct][nt] = __builtin_amdgcn_mfma_f32_16x16x32_f16(afP[kc & 1][ct], bf, hacc[ct][nt], 0, 0, 0);
                }
                __builtin_amdgcn_s_setprio(0);
            }
        }

        __syncthreads();   // all s_X reads done before overlaying s_H

        // bias + relu + stage h -> s_H frag layout (oq = 2w + (ct>>1))
        {
            f32x4 bb[4];
            #pragma unroll
            for (int ct = 0; ct < 4; ++ct)
                bb[ct] = *(const f32x4*)(b1v + w * 64 + ct * 16 + quad * 4);
            #pragma unroll
            for (int ct = 0; ct < 4; ++ct) {
                const int oq = 2 * w + (ct >> 1);
                const int lp = l16 + 16 * (((ct & 1) * 2) + (quad >> 1));
                const int jo = (quad & 1) * 4;
                #pragma unroll
                for (int nt = 0; nt < 4; ++nt) {
                    const f32x4 v = hacc[ct][nt];
                    f16x4 hv;
                    hv[0] = (_Float16)fmaxf(v[0] + bb[ct][0], 0.f);
                    hv[1] = (_Float16)fmaxf(v[1] + bb[ct][1], 0.f);
                    hv[2] = (_Float16)fmaxf(v[2] + bb[ct][2], 0.f);
                    hv[3] = (_Float16)fmaxf(v[3] + bb[ct][3], 0.f);
                    *(f16x4*)(s_H + ((oq * 4 + nt) * 64 + lp) * 8 + jo) = hv;
                }
            }
        }
        __syncthreads();

        // ---------------- Phase C: out = relu(W2 @ h + b2), K=256 ----------
        f32x4 oacc[2][4];
        #pragma unroll
        for (int ct = 0; ct < 2; ++ct)
            #pragma unroll
            for (int nt = 0; nt < 4; ++nt)
                oacc[ct][nt] = (f32x4){0.f, 0.f, 0.f, 0.f};

        {
            f16x8 afP2[2][2];  // ping-pong
            loadW2(0, afP2[0]);
            #pragma unroll
            for (int oc = 0; oc < 8; ++oc) {
                if (oc + 1 < 8) loadW2(oc + 1, afP2[(oc + 1) & 1]);
                __builtin_amdgcn_s_setprio(1);
                #pragma unroll
                for (int nt = 0; nt < 4; ++nt) {
                    const f16x8 bf = *(const f16x8*)(s_H + ((oc * 4 + nt) * 64 + L) * 8);
                    #pragma unroll
                    for (int ct = 0; ct < 2; ++ct)
                        oacc[ct][nt] = __builtin_amdgcn_mfma_f32_16x16x32_f16(afP2[oc & 1][ct], bf, oacc[ct][nt], 0, 0, 0);
                }
                __builtin_amdgcn_s_setprio(0);
            }
        }

        // epilogue: bias + relu + store
        {
            f32x4 bb2[2];
            #pragma unroll
            for (int ct = 0; ct < 2; ++ct)
                bb2[ct] = *(const f32x4*)(b2v + w * 32 + ct * 16 + quad * 4);
            #pragma unroll
            for (int ct = 0; ct < 2; ++ct)
                #pragma unroll
                for (int nt = 0; nt < 4; ++nt) {
                    float* op = out + ((size_t)b * H2c + w * 32 + ct * 16 + quad * 4) * NPTS
                                    + n0 + nt * 16 + l16;
                    #pragma unroll
                    for (int j = 0; j < 4; ++j)
                        op[(size_t)j * NPTS] = fmaxf(oacc[ct][nt][j] + bb2[ct][j], 0.f);
                }
        }
    }
}

extern "C" void kernel_launch(void* const* d_in, const int* in_sizes, int n_in,
                              void* d_out, int out_size, void* d_ws, size_t ws_size,
                              hipStream_t stream) {
    (void)in_sizes; (void)n_in; (void)out_size;
    const float* xyz1 = (const float*)d_in[0];
    const float* xyz2 = (const float*)d_in[1];
    const float* p1   = (const float*)d_in[2];
    const float* p2   = (const float*)d_in[3];
    const float* W1   = (const float*)d_in[4];
    const float* b1   = (const float*)d_in[5];
    const float* W2   = (const float*)d_in[6];
    const float* b2   = (const float*)d_in[7];
    float* out = (float*)d_out;

    dim3 grid(BBATCH * (NPTS / TN) / 2);   // 512 blocks x 2 tiles = exactly 2/CU, no tail
    dim3 block(256);
    if (ws_size >= (size_t)WS_F16_TOTAL * 2) {
        _Float16* ws = (_Float16*)d_ws;
        const int nswz = NFRAG_P2 + NFRAG_W1 + NFRAG_W2;   // 540672 = 2112 * 256
        cvt_swz<<<dim3(nswz / 256), dim3(256), 0, stream>>>(p2, W1, W2, ws);
        fp_mfma10<true><<<grid, block, 0, stream>>>(xyz1, xyz2, p1, p2, W1, b1, W2, b2,
                                                    ws + WS_P2S, ws + WS_W1S, ws + WS_W2S, out);
    } else {
        fp_mfma10<false><<<grid, block, 0, stream>>>(xyz1, xyz2, p1, p2, W1, b1, W2, b2,
                                                     nullptr, nullptr, nullptr, out);
    }
}

// Round 4
// 162.620 us; speedup vs baseline: 1.3315x; 1.3315x over previous
//
#include <hip/hip_runtime.h>
#include <math.h>

// Problem constants (from reference setup_inputs)
#define BBATCH 16
#define NPTS   4096
#define MPTS   1024
#define C1c    128
#define C2c    256
#define CINc   384
#define H1c    256
#define H2c    128
#define TN     64

typedef _Float16 f16x8 __attribute__((ext_vector_type(8)));
typedef _Float16 f16x4 __attribute__((ext_vector_type(4)));
typedef float    f32x4 __attribute__((ext_vector_type(4)));

// ---- LDS layout (bytes) ---------------------------------------------------
// union [0,49152):
//   phase A: inv dbuf 2 x [4 cc][4 nt][64 lane][8 f16] = 32768 B
//            s_xyz2 [1024][3] f32 = 12288 B at 32768 (dead after last gen;
//            interp overlays it — writes land after the reduction barriers)
//   phase B: s_X frags [12 kc][4 nt][64][8] f16 = 49152 B
//   phase C: s_H frags [8 oc][4 nt][64][8] f16 = 32768 B
// s_red 512 f32 at 49152 (recip overlaid in first 64)
// Total 51200 B. 512-thread blocks, 2 blocks/CU (102.4 KB) = 16 waves/CU
// = 4 waves/SIMD; grid 1024 = exactly 2 full rounds, no partial tail.
#define INV_HALF   8192            // f16 elems per inv buffer (16384 B)
#define OFF_XYZ2   32768
#define OFF_RED    49152
#define SMEM_BYTES 51200

// ---- fragment-swizzled workspace layout (f16 elements), unchanged ----
//   p2s: frag ((b*32+s)*16 + wt)*64 + lane : (c=wt*16+(lane&15), m=s*32+(lane>>4)*8+i)
//   W1s: frag (wt*12 + kc)*64 + lane       : (o=wt*16+(lane&15), k=kc*32+(lane>>4)*8+i)
//   W2s: frag (wt2*8 + oc)*64 + lane       : (o=wt2*16+(lane&15), k=oc*32+(lane>>4)*8+i)
#define NFRAG_P2  (BBATCH * 32 * 16 * 64)        // 524288
#define NFRAG_W1  (16 * 12 * 64)                 // 12288
#define NFRAG_W2  (8 * 8 * 64)                   // 4096
#define WS_P2S  0
#define WS_W1S  (NFRAG_P2 * 8)                   // 4194304
#define WS_W2S  (WS_W1S + NFRAG_W1 * 8)
#define WS_F16_TOTAL (WS_W2S + NFRAG_W2 * 8)     // 4325376 f16 = 8650752 B

// ---------------------------------------------------------------------------
// pre-pass: convert + swizzle p2 / W1 / W2 into fragment-contiguous f16
__global__ __launch_bounds__(256) void cvt_swz(
    const float* __restrict__ p2, const float* __restrict__ W1,
    const float* __restrict__ W2, _Float16* __restrict__ ws)
{
    const int t = blockIdx.x * 256 + threadIdx.x;   // one fragment (8 f16) per thread
    const float* src;
    _Float16* dst;
    if (t < NFRAG_P2) {
        const int lane = t & 63, wt = (t >> 6) & 15, s = (t >> 10) & 31, b = t >> 15;
        const int c = wt * 16 + (lane & 15);
        const int m = s * 32 + (lane >> 4) * 8;
        src = p2 + ((size_t)(b * C2c + c)) * MPTS + m;
        dst = ws + WS_P2S + (size_t)t * 8;
    } else if (t < NFRAG_P2 + NFRAG_W1) {
        const int u = t - NFRAG_P2;
        const int lane = u & 63, kc = (u >> 6) % 12, wt = (u >> 6) / 12;
        const int o = wt * 16 + (lane & 15);
        const int k = kc * 32 + (lane >> 4) * 8;
        src = W1 + (size_t)o * CINc + k;
        dst = ws + WS_W1S + (size_t)u * 8;
    } else {
        const int v = t - NFRAG_P2 - NFRAG_W1;
        const int lane = v & 63, oc = (v >> 6) & 7, wt2 = v >> 9;
        const int o = wt2 * 16 + (lane & 15);
        const int k = oc * 32 + (lane >> 4) * 8;
        src = W2 + (size_t)o * H1c + k;
        dst = ws + WS_W2S + (size_t)v * 8;
    }
    const float4 a0 = *(const float4*)(src);
    const float4 a1 = *(const float4*)(src + 4);
    f16x8 h;
    h[0] = (_Float16)a0.x; h[1] = (_Float16)a0.y; h[2] = (_Float16)a0.z; h[3] = (_Float16)a0.w;
    h[4] = (_Float16)a1.x; h[5] = (_Float16)a1.y; h[6] = (_Float16)a1.z; h[7] = (_Float16)a1.w;
    *(f16x8*)dst = h;
}

// ---------------------------------------------------------------------------
// R11: more TLP at LOWER per-thread register pressure (the R8/R10 lesson:
// anything needing >~136 regs spills). 8 waves per block on the same 64-n
// tile: per-thread state halves (acc 64->32 regs), fitting the 128-reg cap
// that 4 waves/SIMD requires. 16 waves/CU vs R9's 12, and a perfectly
// balanced 2-round schedule (1024 blocks at 2 resident/CU). Dataflow,
// frag layouts, ping-pong prefetch, setprio, XCD swizzle: unchanged from R9.
template <bool F16P>
__global__ __launch_bounds__(512, 4) void fp_mfma11(
    const float* __restrict__ xyz1, const float* __restrict__ xyz2,
    const float* __restrict__ p1,   const float* __restrict__ p2,
    const float* __restrict__ W1,   const float* __restrict__ b1v,
    const float* __restrict__ W2,   const float* __restrict__ b2v,
    const _Float16* __restrict__ p2s, const _Float16* __restrict__ W1s,
    const _Float16* __restrict__ W2s,
    float* __restrict__ out)
{
    __shared__ __align__(16) char smem[SMEM_BYTES];
    _Float16* s_inv  = (_Float16*)smem;
    _Float16* s_X    = (_Float16*)smem;
    _Float16* s_H    = (_Float16*)smem;
    float*    s_xyz2 = (float*)(smem + OFF_XYZ2);
    float*    s_red  = (float*)(smem + OFF_RED);

    const int tid  = threadIdx.x;
    const int w    = tid >> 6;    // wave 0..7
    const int L    = tid & 63;
    const int quad = L >> 4;
    const int l16  = L & 15;

    // XCD swizzle: each XCD sees 2 batches -> p2s working set (1 MB) L2-resident
    const int id = blockIdx.x;            // 1024 blocks
    const int b  = (id & 7) * 2 + ((id >> 3) & 1);
    const int n0 = (id >> 4) * TN;

    const float* __restrict__ z2b = xyz2 + (size_t)b * MPTS * 3;
    const float* __restrict__ p2b = p2   + (size_t)b * C2c * MPTS;
    const _Float16* __restrict__ p2sb =
        F16P ? (p2s + (((size_t)b * 32 * 16 + (size_t)w * 2) * 64 + L) * 8) : (const _Float16*)nullptr;

    // stage xyz2 (12 KB, coalesced f32x4) — 512 threads: 1.5 vec loads each
    for (int i = tid; i < MPTS * 3 / 4; i += 512)
        ((f32x4*)s_xyz2)[i] = ((const f32x4*)z2b)[i];

    const float x1x = xyz1[((size_t)b * NPTS + n0 + L) * 3 + 0];
    const float x1y = xyz1[((size_t)b * NPTS + n0 + L) * 3 + 1];
    const float x1z = xyz1[((size_t)b * NPTS + n0 + L) * 3 + 2];

    f32x4 acc[2][4];   // [ct][nt]: row c = w*32+ct*16+quad*4+r, col n = nt*16+l16
    #pragma unroll
    for (int ct = 0; ct < 2; ++ct)
        #pragma unroll
        for (int nt = 0; nt < 4; ++nt)
            acc[ct][nt] = (f32x4){0.f, 0.f, 0.f, 0.f};

    float ssum = 0.f;
    f16x8 Aa[2][2];    // A-frag ping-pong, parity = chunk index & 1

    auto loadA = [&](int s, f16x8 dst[2]) {
        if (F16P) {
            const _Float16* ap = p2sb + (size_t)s * (16 * 64 * 8);
            #pragma unroll
            for (int ct = 0; ct < 2; ++ct)
                dst[ct] = *(const f16x8*)(ap + (size_t)ct * (64 * 8));
        } else {
            const float* ap = p2b + (size_t)(w * 32 + l16) * MPTS + s * 32 + quad * 8;
            #pragma unroll
            for (int ct = 0; ct < 2; ++ct) {
                const float4 a0 = *(const float4*)(ap + (size_t)ct * (16 * MPTS));
                const float4 a1 = *(const float4*)(ap + (size_t)ct * (16 * MPTS) + 4);
                f16x8 h;
                h[0] = (_Float16)a0.x; h[1] = (_Float16)a0.y; h[2] = (_Float16)a0.z; h[3] = (_Float16)a0.w;
                h[4] = (_Float16)a1.x; h[5] = (_Float16)a1.y; h[6] = (_Float16)a1.z; h[7] = (_Float16)a1.w;
                dst[ct] = h;
            }
        }
    };

    // one 8-m group of super-chunk ss_ into frag buffer (ss_&1), g in {0,1}:
    // thread (w,L): n=L, m = ss_*128 + w*16 + g*8 + i
    //   -> frag (cc = w>>1, nt = quad), k-slot q' = (w&1)*2+g, lane l16.
    auto gen_g = [&](int ss_, int g) {
        _Float16* buf = s_inv + (ss_ & 1) * INV_HALF;
        const float* zp = s_xyz2 + (size_t)(ss_ * 128 + w * 16 + g * 8) * 3;
        f32x4 zr[6];
        #pragma unroll
        for (int j = 0; j < 6; ++j) zr[j] = ((const f32x4*)zp)[j];
        const float* zv = (const float*)zr;
        f16x8 iv;
        #pragma unroll
        for (int i = 0; i < 8; ++i) {
            const float dx = x1x - zv[3 * i + 0];
            const float dy = x1y - zv[3 * i + 1];
            const float dz = x1z - zv[3 * i + 2];
            const float d2 = fmaf(dx, dx, fmaf(dy, dy, fmaf(dz, dz, 1e-12f)));
            const float inv = __builtin_amdgcn_rsqf(d2);
            ssum += inv;
            iv[i] = (_Float16)inv;
        }
        *(f16x8*)(buf + ((((w >> 1) * 4 + quad) * 64) + ((w & 1) * 2 + g) * 16 + l16) * 8) = iv;
    };

    loadA(0, Aa[0]);
    __syncthreads();   // xyz2 staged
    gen_g(0, 0);
    gen_g(0, 1);
    __syncthreads();   // super-chunk 0 visible

    for (int ss = 0; ss < 8; ++ss) {
        const _Float16* buf = s_inv + (ss & 1) * INV_HALF;
        #pragma unroll
        for (int cc = 0; cc < 4; ++cc) {
            const int s = ss * 4 + cc;
            if (s + 1 < 32) loadA(s + 1, Aa[(cc + 1) & 1]);   // barrier-free prefetch
            if (ss + 1 < 8 && cc < 2) gen_g(ss + 1, cc);      // inv VALU interleaved
            __builtin_amdgcn_s_setprio(1);
            #pragma unroll
            for (int nt = 0; nt < 4; ++nt) {
                const f16x8 bf = *(const f16x8*)(buf + ((cc * 4 + nt) * 64 + L) * 8);
                #pragma unroll
                for (int ct = 0; ct < 2; ++ct)
                    acc[ct][nt] = __builtin_amdgcn_mfma_f32_16x16x32_f16(Aa[cc & 1][ct], bf, acc[ct][nt], 0, 0, 0);
            }
            __builtin_amdgcn_s_setprio(0);
        }
        __syncthreads();   // reads of buf(ss) done; writes of buf(ss+1) done
    }

    // p1 -> s_X frags kq 0..3 (bytes [0,16K) = dead inv buf0). Each thread
    // fills 2 frag slots f = w*2+h; issued BEFORE the reduction so the 16
    // global loads hide under reduction+interp.
    {
        #pragma unroll
        for (int h = 0; h < 2; ++h) {
            const int f  = w * 2 + h;      // 0..15
            const int kq = f >> 2, nt = f & 3;
            const float* pp = p1 + ((size_t)b * C1c + kq * 32 + quad * 8) * NPTS + n0 + nt * 16 + l16;
            float tv[8];
            #pragma unroll
            for (int j = 0; j < 8; ++j) tv[j] = pp[(size_t)j * NPTS];
            f16x8 v;
            #pragma unroll
            for (int j = 0; j < 8; ++j) v[j] = (_Float16)tv[j];
            *(f16x8*)(s_X + ((size_t)f * 64 + L) * 8) = v;
        }
    }

    // ---- S[n] reduction over the 8 m-slice partials; recip in s_red[0..63]
    s_red[tid] = ssum;
    __syncthreads();
    if (tid < 64) {
        float s = 0.f;
        #pragma unroll
        for (int wv = 0; wv < 8; ++wv) s += s_red[wv * 64 + tid];
        s_red[tid] = 1.0f / s;
    }
    __syncthreads();   // recip ready; phase-A scratch dead -> interp overlay safe

    // interp -> s_X frags kq = 4 + w (bytes [16K,48K): dead buf1 + dead xyz2).
    //   value (n = nt*16+l16, c = w*32+ct*16+quad*4+r):
    //   lane slot = (ct*2 + (quad>>1))*16 + l16, elem offset (quad&1)*4 + r.
    {
        float rn4[4];
        #pragma unroll
        for (int nt = 0; nt < 4; ++nt) rn4[nt] = s_red[nt * 16 + l16];
        #pragma unroll
        for (int ct = 0; ct < 2; ++ct) {
            const int kq = 4 + w;
            const int lp = (ct * 2 + (quad >> 1)) * 16 + l16;
            const int jo = (quad & 1) * 4;
            #pragma unroll
            for (int nt = 0; nt < 4; ++nt) {
                const f32x4 v = acc[ct][nt];
                const float r = rn4[nt];
                f16x4 hv;
                hv[0] = (_Float16)(v[0] * r);
                hv[1] = (_Float16)(v[1] * r);
                hv[2] = (_Float16)(v[2] * r);
                hv[3] = (_Float16)(v[3] * r);
                *(f16x4*)(s_X + (((size_t)(kq * 4 + nt)) * 64 + lp) * 8 + jo) = hv;
            }
        }
    }
    __syncthreads();   // full X (p1 + interp) frags complete

    // ---------------- Phase B: h = relu(W1 @ X + b1), K=384 ----------------
    f32x4 hacc[2][4];
    #pragma unroll
    for (int ct = 0; ct < 2; ++ct)
        #pragma unroll
        for (int nt = 0; nt < 4; ++nt)
            hacc[ct][nt] = (f32x4){0.f, 0.f, 0.f, 0.f};

    auto loadW1 = [&](int kc, f16x8 dst[2]) {
        if (F16P) {
            const _Float16* wp = W1s + (((size_t)(w * 2) * 12 + kc) * 64 + L) * 8;
            #pragma unroll
            for (int ct = 0; ct < 2; ++ct)
                dst[ct] = *(const f16x8*)(wp + (size_t)ct * (12 * 64 * 8));
        } else {
            const float* wp = W1 + (size_t)(w * 32 + l16) * CINc + kc * 32 + quad * 8;
            #pragma unroll
            for (int ct = 0; ct < 2; ++ct) {
                const float4 a0 = *(const float4*)(wp + ct * (16 * CINc));
                const float4 a1 = *(const float4*)(wp + ct * (16 * CINc) + 4);
                f16x8 h;
                h[0] = (_Float16)a0.x; h[1] = (_Float16)a0.y; h[2] = (_Float16)a0.z; h[3] = (_Float16)a0.w;
                h[4] = (_Float16)a1.x; h[5] = (_Float16)a1.y; h[6] = (_Float16)a1.z; h[7] = (_Float16)a1.w;
                dst[ct] = h;
            }
        }
    };

    {
        f16x8 afP[2][2];   // ping-pong, static kc&1 indexing (full unroll)
        loadW1(0, afP[0]);
        #pragma unroll
        for (int kc = 0; kc < 12; ++kc) {
            if (kc + 1 < 12) loadW1(kc + 1, afP[(kc + 1) & 1]);
            __builtin_amdgcn_s_setprio(1);
            #pragma unroll
            for (int nt = 0; nt < 4; ++nt) {
                const f16x8 bf = *(const f16x8*)(s_X + (((size_t)(kc * 4 + nt)) * 64 + L) * 8);
                #pragma unroll
                for (int ct = 0; ct < 2; ++ct)
                    hacc[ct][nt] = __builtin_amdgcn_mfma_f32_16x16x32_f16(afP[kc & 1][ct], bf, hacc[ct][nt], 0, 0, 0);
            }
            __builtin_amdgcn_s_setprio(0);
        }
    }

    __syncthreads();   // all s_X reads done before overlaying s_H

    // bias + relu + stage h -> s_H frag layout (oq = w, same slot math as interp)
    {
        f32x4 bb[2];
        #pragma unroll
        for (int ct = 0; ct < 2; ++ct)
            bb[ct] = *(const f32x4*)(b1v + w * 32 + ct * 16 + quad * 4);
        #pragma unroll
        for (int ct = 0; ct < 2; ++ct) {
            const int lp = (ct * 2 + (quad >> 1)) * 16 + l16;
            const int jo = (quad & 1) * 4;
            #pragma unroll
            for (int nt = 0; nt < 4; ++nt) {
                const f32x4 v = hacc[ct][nt];
                f16x4 hv;
                hv[0] = (_Float16)fmaxf(v[0] + bb[ct][0], 0.f);
                hv[1] = (_Float16)fmaxf(v[1] + bb[ct][1], 0.f);
                hv[2] = (_Float16)fmaxf(v[2] + bb[ct][2], 0.f);
                hv[3] = (_Float16)fmaxf(v[3] + bb[ct][3], 0.f);
                *(f16x4*)(s_H + (((size_t)(w * 4 + nt)) * 64 + lp) * 8 + jo) = hv;
            }
        }
    }
    __syncthreads();

    // ---------------- Phase C: out = relu(W2 @ h + b2), K=256 --------------
    f32x4 oacc[4];
    #pragma unroll
    for (int nt = 0; nt < 4; ++nt)
        oacc[nt] = (f32x4){0.f, 0.f, 0.f, 0.f};

    auto loadW2 = [&](int oc, f16x8& dst) {
        if (F16P) {
            dst = *(const f16x8*)(W2s + (((size_t)(w * 8 + oc)) * 64 + L) * 8);
        } else {
            const float* wp = W2 + (size_t)(w * 16 + l16) * H1c + oc * 32 + quad * 8;
            const float4 a0 = *(const float4*)(wp);
            const float4 a1 = *(const float4*)(wp + 4);
            f16x8 h;
            h[0] = (_Float16)a0.x; h[1] = (_Float16)a0.y; h[2] = (_Float16)a0.z; h[3] = (_Float16)a0.w;
            h[4] = (_Float16)a1.x; h[5] = (_Float16)a1.y; h[6] = (_Float16)a1.z; h[7] = (_Float16)a1.w;
            dst = h;
        }
    };

    {
        f16x8 afP2[2];     // ping-pong
        loadW2(0, afP2[0]);
        #pragma unroll
        for (int oc = 0; oc < 8; ++oc) {
            if (oc + 1 < 8) loadW2(oc + 1, afP2[(oc + 1) & 1]);
            __builtin_amdgcn_s_setprio(1);
            #pragma unroll
            for (int nt = 0; nt < 4; ++nt) {
                const f16x8 bf = *(const f16x8*)(s_H + (((size_t)(oc * 4 + nt)) * 64 + L) * 8);
                oacc[nt] = __builtin_amdgcn_mfma_f32_16x16x32_f16(afP2[oc & 1], bf, oacc[nt], 0, 0, 0);
            }
            __builtin_amdgcn_s_setprio(0);
        }
    }

    // epilogue: bias + relu + store (o = w*16 + quad*4 + j)
    {
        const f32x4 bb2 = *(const f32x4*)(b2v + w * 16 + quad * 4);
        #pragma unroll
        for (int nt = 0; nt < 4; ++nt) {
            float* op = out + ((size_t)b * H2c + w * 16 + quad * 4) * NPTS
                            + n0 + nt * 16 + l16;
            #pragma unroll
            for (int j = 0; j < 4; ++j)
                op[(size_t)j * NPTS] = fmaxf(oacc[nt][j] + bb2[j], 0.f);
        }
    }
}

extern "C" void kernel_launch(void* const* d_in, const int* in_sizes, int n_in,
                              void* d_out, int out_size, void* d_ws, size_t ws_size,
                              hipStream_t stream) {
    (void)in_sizes; (void)n_in; (void)out_size;
    const float* xyz1 = (const float*)d_in[0];
    const float* xyz2 = (const float*)d_in[1];
    const float* p1   = (const float*)d_in[2];
    const float* p2   = (const float*)d_in[3];
    const float* W1   = (const float*)d_in[4];
    const float* b1   = (const float*)d_in[5];
    const float* W2   = (const float*)d_in[6];
    const float* b2   = (const float*)d_in[7];
    float* out = (float*)d_out;

    dim3 grid(BBATCH * (NPTS / TN));   // 1024 blocks @ 2 resident/CU = 2 exact rounds
    dim3 block(512);
    if (ws_size >= (size_t)WS_F16_TOTAL * 2) {
        _Float16* ws = (_Float16*)d_ws;
        const int nswz = NFRAG_P2 + NFRAG_W1 + NFRAG_W2;   // 540672 = 2112 * 256
        cvt_swz<<<dim3(nswz / 256), dim3(256), 0, stream>>>(p2, W1, W2, ws);
        fp_mfma11<true><<<grid, block, 0, stream>>>(xyz1, xyz2, p1, p2, W1, b1, W2, b2,
                                                    ws + WS_P2S, ws + WS_W1S, ws + WS_W2S, out);
    } else {
        fp_mfma11<false><<<grid, block, 0, stream>>>(xyz1, xyz2, p1, p2, W1, b1, W2, b2,
                                                     nullptr, nullptr, nullptr, out);
    }
}

// Round 5
// 161.917 us; speedup vs baseline: 1.3373x; 1.0043x over previous
//
#include <hip/hip_runtime.h>
#include <math.h>

// Problem constants (from reference setup_inputs)
#define BBATCH 16
#define NPTS   4096
#define MPTS   1024
#define C1c    128
#define C2c    256
#define CINc   384
#define H1c    256
#define H2c    128
#define TN     64

typedef _Float16 f16x8 __attribute__((ext_vector_type(8)));
typedef _Float16 f16x4 __attribute__((ext_vector_type(4)));
typedef float    f32x4 __attribute__((ext_vector_type(4)));

// Raw barrier: drain LDS ops only (gen ds_writes must be visible), but leave
// global prefetch loads IN FLIGHT across the barrier. __syncthreads() would
// emit s_waitcnt vmcnt(0) and force-drain the A-frag prefetch every super-step
// (HK-verified pattern, learn_hip m194-m199).
#define BAR() do { asm volatile("s_waitcnt lgkmcnt(0)" ::: "memory"); \
                   __builtin_amdgcn_s_barrier(); } while (0)

// ---- LDS layout (bytes) ---------------------------------------------------
// union [0,49152):
//   phase A: inv dbuf 2 x [4 cc][4 nt][64 lane][8 f16] = 32768 B
//            s_xyz2 [1024][3] f32 = 12288 B at 32768 (dead after last gen)
//   phase B: s_X frags [12 kc][4 nt][64][8] f16 = 49152 B
//   phase C: s_H frags [8 oc][4 nt][64][8] f16 = 32768 B
// s_red 512 f32 at 49152 (recip overlaid in first 64)
// Total 51200 B. 512-thread blocks, 2 blocks/CU = 16 waves/CU = 4 waves/SIMD;
// grid 1024 = exactly 2 full rounds, no partial tail.
#define INV_HALF   8192            // f16 elems per inv buffer (16384 B)
#define OFF_XYZ2   32768
#define OFF_RED    49152
#define SMEM_BYTES 51200

// ---- fragment-swizzled workspace layout (f16 elements), unchanged ----
#define NFRAG_P2  (BBATCH * 32 * 16 * 64)        // 524288
#define NFRAG_W1  (16 * 12 * 64)                 // 12288
#define NFRAG_W2  (8 * 8 * 64)                   // 4096
#define WS_P2S  0
#define WS_W1S  (NFRAG_P2 * 8)                   // 4194304
#define WS_W2S  (WS_W1S + NFRAG_W1 * 8)
#define WS_F16_TOTAL (WS_W2S + NFRAG_W2 * 8)     // 4325376 f16 = 8650752 B

// ---------------------------------------------------------------------------
// pre-pass: convert + swizzle p2 / W1 / W2 into fragment-contiguous f16
__global__ __launch_bounds__(256) void cvt_swz(
    const float* __restrict__ p2, const float* __restrict__ W1,
    const float* __restrict__ W2, _Float16* __restrict__ ws)
{
    const int t = blockIdx.x * 256 + threadIdx.x;   // one fragment (8 f16) per thread
    const float* src;
    _Float16* dst;
    if (t < NFRAG_P2) {
        const int lane = t & 63, wt = (t >> 6) & 15, s = (t >> 10) & 31, b = t >> 15;
        const int c = wt * 16 + (lane & 15);
        const int m = s * 32 + (lane >> 4) * 8;
        src = p2 + ((size_t)(b * C2c + c)) * MPTS + m;
        dst = ws + WS_P2S + (size_t)t * 8;
    } else if (t < NFRAG_P2 + NFRAG_W1) {
        const int u = t - NFRAG_P2;
        const int lane = u & 63, kc = (u >> 6) % 12, wt = (u >> 6) / 12;
        const int o = wt * 16 + (lane & 15);
        const int k = kc * 32 + (lane >> 4) * 8;
        src = W1 + (size_t)o * CINc + k;
        dst = ws + WS_W1S + (size_t)u * 8;
    } else {
        const int v = t - NFRAG_P2 - NFRAG_W1;
        const int lane = v & 63, oc = (v >> 6) & 7, wt2 = v >> 9;
        const int o = wt2 * 16 + (lane & 15);
        const int k = oc * 32 + (lane >> 4) * 8;
        src = W2 + (size_t)o * H1c + k;
        dst = ws + WS_W2S + (size_t)v * 8;
    }
    const float4 a0 = *(const float4*)(src);
    const float4 a1 = *(const float4*)(src + 4);
    f16x8 h;
    h[0] = (_Float16)a0.x; h[1] = (_Float16)a0.y; h[2] = (_Float16)a0.z; h[3] = (_Float16)a0.w;
    h[4] = (_Float16)a1.x; h[5] = (_Float16)a1.y; h[6] = (_Float16)a1.z; h[7] = (_Float16)a1.w;
    *(f16x8*)dst = h;
}

// ---------------------------------------------------------------------------
// R12 = R11 + latency-exposure fixes (VGPR headroom 48/128 permits them):
//  - lgkm-only raw barriers: A-frag prefetch survives across all barriers.
//  - ring-4 A-frag buffer, prefetch distance 2 (+16 regs, no tile doubling).
//  - peeled ss=7: p1 HBM loads issued BEFORE its MFMA block (latency hidden),
//    frag-writes + ssum store after it; one barrier deleted.
//  - W1/W2 frag-0 prefetch issued across the phase-transition barriers.
template <bool F16P>
__global__ __launch_bounds__(512, 4) void fp_mfma12(
    const float* __restrict__ xyz1, const float* __restrict__ xyz2,
    const float* __restrict__ p1,   const float* __restrict__ p2,
    const float* __restrict__ W1,   const float* __restrict__ b1v,
    const float* __restrict__ W2,   const float* __restrict__ b2v,
    const _Float16* __restrict__ p2s, const _Float16* __restrict__ W1s,
    const _Float16* __restrict__ W2s,
    float* __restrict__ out)
{
    __shared__ __align__(16) char smem[SMEM_BYTES];
    _Float16* s_inv  = (_Float16*)smem;
    _Float16* s_X    = (_Float16*)smem;
    _Float16* s_H    = (_Float16*)smem;
    float*    s_xyz2 = (float*)(smem + OFF_XYZ2);
    float*    s_red  = (float*)(smem + OFF_RED);

    const int tid  = threadIdx.x;
    const int w    = tid >> 6;    // wave 0..7
    const int L    = tid & 63;
    const int quad = L >> 4;
    const int l16  = L & 15;

    // XCD swizzle: each XCD sees 2 batches -> p2s working set (1 MB) L2-resident
    const int id = blockIdx.x;            // 1024 blocks
    const int b  = (id & 7) * 2 + ((id >> 3) & 1);
    const int n0 = (id >> 4) * TN;

    const float* __restrict__ z2b = xyz2 + (size_t)b * MPTS * 3;
    const float* __restrict__ p2b = p2   + (size_t)b * C2c * MPTS;
    const _Float16* __restrict__ p2sb =
        F16P ? (p2s + (((size_t)b * 32 * 16 + (size_t)w * 2) * 64 + L) * 8) : (const _Float16*)nullptr;

    // stage xyz2 (12 KB, coalesced f32x4)
    for (int i = tid; i < MPTS * 3 / 4; i += 512)
        ((f32x4*)s_xyz2)[i] = ((const f32x4*)z2b)[i];

    const float x1x = xyz1[((size_t)b * NPTS + n0 + L) * 3 + 0];
    const float x1y = xyz1[((size_t)b * NPTS + n0 + L) * 3 + 1];
    const float x1z = xyz1[((size_t)b * NPTS + n0 + L) * 3 + 2];

    f32x4 acc[2][4];   // [ct][nt]: row c = w*32+ct*16+quad*4+r, col n = nt*16+l16
    #pragma unroll
    for (int ct = 0; ct < 2; ++ct)
        #pragma unroll
        for (int nt = 0; nt < 4; ++nt)
            acc[ct][nt] = (f32x4){0.f, 0.f, 0.f, 0.f};

    float ssum = 0.f;
    f16x8 Aa[4][2];    // A-frag ring, slot = chunk & 3 (prefetch distance 2)

    auto loadA = [&](int s, f16x8 dst[2]) {
        if (F16P) {
            const _Float16* ap = p2sb + (size_t)s * (16 * 64 * 8);
            #pragma unroll
            for (int ct = 0; ct < 2; ++ct)
                dst[ct] = *(const f16x8*)(ap + (size_t)ct * (64 * 8));
        } else {
            const float* ap = p2b + (size_t)(w * 32 + l16) * MPTS + s * 32 + quad * 8;
            #pragma unroll
            for (int ct = 0; ct < 2; ++ct) {
                const float4 a0 = *(const float4*)(ap + (size_t)ct * (16 * MPTS));
                const float4 a1 = *(const float4*)(ap + (size_t)ct * (16 * MPTS) + 4);
                f16x8 h;
                h[0] = (_Float16)a0.x; h[1] = (_Float16)a0.y; h[2] = (_Float16)a0.z; h[3] = (_Float16)a0.w;
                h[4] = (_Float16)a1.x; h[5] = (_Float16)a1.y; h[6] = (_Float16)a1.z; h[7] = (_Float16)a1.w;
                dst[ct] = h;
            }
        }
    };

    // one 8-m group of super-chunk ss_ into frag buffer (ss_&1), g in {0,1}:
    // thread (w,L): n=L, m = ss_*128 + w*16 + g*8 + i
    //   -> frag (cc = w>>1, nt = quad), k-slot q' = (w&1)*2+g, lane l16.
    auto gen_g = [&](int ss_, int g) {
        _Float16* buf = s_inv + (ss_ & 1) * INV_HALF;
        const float* zp = s_xyz2 + (size_t)(ss_ * 128 + w * 16 + g * 8) * 3;
        f32x4 zr[6];
        #pragma unroll
        for (int j = 0; j < 6; ++j) zr[j] = ((const f32x4*)zp)[j];
        const float* zv = (const float*)zr;
        f16x8 iv;
        #pragma unroll
        for (int i = 0; i < 8; ++i) {
            const float dx = x1x - zv[3 * i + 0];
            const float dy = x1y - zv[3 * i + 1];
            const float dz = x1z - zv[3 * i + 2];
            const float d2 = fmaf(dx, dx, fmaf(dy, dy, fmaf(dz, dz, 1e-12f)));
            const float inv = __builtin_amdgcn_rsqf(d2);
            ssum += inv;
            iv[i] = (_Float16)inv;
        }
        *(f16x8*)(buf + ((((w >> 1) * 4 + quad) * 64) + ((w & 1) * 2 + g) * 16 + l16) * 8) = iv;
    };

    loadA(0, Aa[0]);
    loadA(1, Aa[1]);
    BAR();             // xyz2 staged (lgkm drain; A-prefetch stays in flight)
    gen_g(0, 0);
    gen_g(0, 1);
    BAR();             // super-chunk 0 visible

    // ---- main phase-A loop: ss = 0..6 (ss = 7 peeled below) ----
    for (int ss = 0; ss < 7; ++ss) {
        const _Float16* buf = s_inv + (ss & 1) * INV_HALF;
        #pragma unroll
        for (int cc = 0; cc < 4; ++cc) {
            const int s = ss * 4 + cc;
            loadA(s + 2, Aa[(cc + 2) & 3]);   // distance-2 ring prefetch (s+2 <= 29)
            if (cc < 2) gen_g(ss + 1, cc);    // inv VALU interleaved
            __builtin_amdgcn_s_setprio(1);
            #pragma unroll
            for (int nt = 0; nt < 4; ++nt) {
                const f16x8 bf = *(const f16x8*)(buf + ((cc * 4 + nt) * 64 + L) * 8);
                #pragma unroll
                for (int ct = 0; ct < 2; ++ct)
                    acc[ct][nt] = __builtin_amdgcn_mfma_f32_16x16x32_f16(Aa[cc][ct], bf, acc[ct][nt], 0, 0, 0);
            }
            __builtin_amdgcn_s_setprio(0);
        }
        BAR();   // reads of buf(ss) done; writes of buf(ss+1) done; vm loads live
    }

    // ---- peeled ss = 7: p1 loads issued first, hidden under the MFMAs ----
    float tv[2][8];
    {
        #pragma unroll
        for (int h = 0; h < 2; ++h) {
            const int f  = w * 2 + h;      // 0..15
            const int kq = f >> 2, nt = f & 3;
            const float* pp = p1 + ((size_t)b * C1c + kq * 32 + quad * 8) * NPTS + n0 + nt * 16 + l16;
            #pragma unroll
            for (int j = 0; j < 8; ++j) tv[h][j] = pp[(size_t)j * NPTS];
        }
    }
    {
        const _Float16* buf = s_inv + INV_HALF;   // 7 & 1 = 1
        #pragma unroll
        for (int cc = 0; cc < 4; ++cc) {
            if (cc < 2) loadA(28 + cc + 2, Aa[(cc + 2) & 3]);   // chunks 30, 31
            __builtin_amdgcn_s_setprio(1);
            #pragma unroll
            for (int nt = 0; nt < 4; ++nt) {
                const f16x8 bf = *(const f16x8*)(buf + ((cc * 4 + nt) * 64 + L) * 8);
                #pragma unroll
                for (int ct = 0; ct < 2; ++ct)
                    acc[ct][nt] = __builtin_amdgcn_mfma_f32_16x16x32_f16(Aa[cc][ct], bf, acc[ct][nt], 0, 0, 0);
            }
            __builtin_amdgcn_s_setprio(0);
        }
    }
    // p1 -> s_X frags kq 0..3 (bytes [0,16K) = buf0; its last reads were ss=6,
    // drained at that barrier). ssum store: s_red is outside the union.
    {
        #pragma unroll
        for (int h = 0; h < 2; ++h) {
            const int f = w * 2 + h;
            f16x8 v;
            #pragma unroll
            for (int j = 0; j < 8; ++j) v[j] = (_Float16)tv[h][j];
            *(f16x8*)(s_X + ((size_t)f * 64 + L) * 8) = v;
        }
    }
    s_red[tid] = ssum;
    BAR();

    // ---- recip over the 8 m-slice partials
    if (tid < 64) {
        float s = 0.f;
        #pragma unroll
        for (int wv = 0; wv < 8; ++wv) s += s_red[wv * 64 + tid];
        s_red[tid] = 1.0f / s;
    }
    BAR();   // recip ready; phase-A scratch dead -> interp overlay safe

    // phase-B prefetch issued now: flies across the interp work + barrier
    f16x8 afP[2][2];
    auto loadW1 = [&](int kc, f16x8 dst[2]) {
        if (F16P) {
            const _Float16* wp = W1s + (((size_t)(w * 2) * 12 + kc) * 64 + L) * 8;
            #pragma unroll
            for (int ct = 0; ct < 2; ++ct)
                dst[ct] = *(const f16x8*)(wp + (size_t)ct * (12 * 64 * 8));
        } else {
            const float* wp = W1 + (size_t)(w * 32 + l16) * CINc + kc * 32 + quad * 8;
            #pragma unroll
            for (int ct = 0; ct < 2; ++ct) {
                const float4 a0 = *(const float4*)(wp + ct * (16 * CINc));
                const float4 a1 = *(const float4*)(wp + ct * (16 * CINc) + 4);
                f16x8 h;
                h[0] = (_Float16)a0.x; h[1] = (_Float16)a0.y; h[2] = (_Float16)a0.z; h[3] = (_Float16)a0.w;
                h[4] = (_Float16)a1.x; h[5] = (_Float16)a1.y; h[6] = (_Float16)a1.z; h[7] = (_Float16)a1.w;
                dst[ct] = h;
            }
        }
    };
    loadW1(0, afP[0]);

    // interp -> s_X frags kq = 4 + w (bytes [16K,48K): dead buf1 + dead xyz2).
    {
        float rn4[4];
        #pragma unroll
        for (int nt = 0; nt < 4; ++nt) rn4[nt] = s_red[nt * 16 + l16];
        #pragma unroll
        for (int ct = 0; ct < 2; ++ct) {
            const int kq = 4 + w;
            const int lp = (ct * 2 + (quad >> 1)) * 16 + l16;
            const int jo = (quad & 1) * 4;
            #pragma unroll
            for (int nt = 0; nt < 4; ++nt) {
                const f32x4 v = acc[ct][nt];
                const float r = rn4[nt];
                f16x4 hv;
                hv[0] = (_Float16)(v[0] * r);
                hv[1] = (_Float16)(v[1] * r);
                hv[2] = (_Float16)(v[2] * r);
                hv[3] = (_Float16)(v[3] * r);
                *(f16x4*)(s_X + (((size_t)(kq * 4 + nt)) * 64 + lp) * 8 + jo) = hv;
            }
        }
    }
    BAR();   // full X (p1 + interp) frags complete; W1 frag-0 still in flight

    // ---------------- Phase B: h = relu(W1 @ X + b1), K=384 ----------------
    f32x4 hacc[2][4];
    #pragma unroll
    for (int ct = 0; ct < 2; ++ct)
        #pragma unroll
        for (int nt = 0; nt < 4; ++nt)
            hacc[ct][nt] = (f32x4){0.f, 0.f, 0.f, 0.f};

    #pragma unroll
    for (int kc = 0; kc < 12; ++kc) {
        if (kc + 1 < 12) loadW1(kc + 1, afP[(kc + 1) & 1]);
        __builtin_amdgcn_s_setprio(1);
        #pragma unroll
        for (int nt = 0; nt < 4; ++nt) {
            const f16x8 bf = *(const f16x8*)(s_X + (((size_t)(kc * 4 + nt)) * 64 + L) * 8);
            #pragma unroll
            for (int ct = 0; ct < 2; ++ct)
                hacc[ct][nt] = __builtin_amdgcn_mfma_f32_16x16x32_f16(afP[kc & 1][ct], bf, hacc[ct][nt], 0, 0, 0);
        }
        __builtin_amdgcn_s_setprio(0);
    }

    BAR();   // all s_X reads done before overlaying s_H

    // phase-C prefetch issued now: flies across h-stage + barrier
    f16x8 afP2[2];
    auto loadW2 = [&](int oc, f16x8& dst) {
        if (F16P) {
            dst = *(const f16x8*)(W2s + (((size_t)(w * 8 + oc)) * 64 + L) * 8);
        } else {
            const float* wp = W2 + (size_t)(w * 16 + l16) * H1c + oc * 32 + quad * 8;
            const float4 a0 = *(const float4*)(wp);
            const float4 a1 = *(const float4*)(wp + 4);
            f16x8 h;
            h[0] = (_Float16)a0.x; h[1] = (_Float16)a0.y; h[2] = (_Float16)a0.z; h[3] = (_Float16)a0.w;
            h[4] = (_Float16)a1.x; h[5] = (_Float16)a1.y; h[6] = (_Float16)a1.z; h[7] = (_Float16)a1.w;
            dst = h;
        }
    };
    loadW2(0, afP2[0]);

    // bias + relu + stage h -> s_H frag layout (oq = w, same slot math as interp)
    {
        f32x4 bb[2];
        #pragma unroll
        for (int ct = 0; ct < 2; ++ct)
            bb[ct] = *(const f32x4*)(b1v + w * 32 + ct * 16 + quad * 4);
        #pragma unroll
        for (int ct = 0; ct < 2; ++ct) {
            const int lp = (ct * 2 + (quad >> 1)) * 16 + l16;
            const int jo = (quad & 1) * 4;
            #pragma unroll
            for (int nt = 0; nt < 4; ++nt) {
                const f32x4 v = hacc[ct][nt];
                f16x4 hv;
                hv[0] = (_Float16)fmaxf(v[0] + bb[ct][0], 0.f);
                hv[1] = (_Float16)fmaxf(v[1] + bb[ct][1], 0.f);
                hv[2] = (_Float16)fmaxf(v[2] + bb[ct][2], 0.f);
                hv[3] = (_Float16)fmaxf(v[3] + bb[ct][3], 0.f);
                *(f16x4*)(s_H + (((size_t)(w * 4 + nt)) * 64 + lp) * 8 + jo) = hv;
            }
        }
    }
    BAR();

    // ---------------- Phase C: out = relu(W2 @ h + b2), K=256 --------------
    f32x4 oacc[4];
    #pragma unroll
    for (int nt = 0; nt < 4; ++nt)
        oacc[nt] = (f32x4){0.f, 0.f, 0.f, 0.f};

    #pragma unroll
    for (int oc = 0; oc < 8; ++oc) {
        if (oc + 1 < 8) loadW2(oc + 1, afP2[(oc + 1) & 1]);
        __builtin_amdgcn_s_setprio(1);
        #pragma unroll
        for (int nt = 0; nt < 4; ++nt) {
            const f16x8 bf = *(const f16x8*)(s_H + (((size_t)(oc * 4 + nt)) * 64 + L) * 8);
            oacc[nt] = __builtin_amdgcn_mfma_f32_16x16x32_f16(afP2[oc & 1], bf, oacc[nt], 0, 0, 0);
        }
        __builtin_amdgcn_s_setprio(0);
    }

    // epilogue: bias + relu + store (o = w*16 + quad*4 + j)
    {
        const f32x4 bb2 = *(const f32x4*)(b2v + w * 16 + quad * 4);
        #pragma unroll
        for (int nt = 0; nt < 4; ++nt) {
            float* op = out + ((size_t)b * H2c + w * 16 + quad * 4) * NPTS
                            + n0 + nt * 16 + l16;
            #pragma unroll
            for (int j = 0; j < 4; ++j)
                op[(size_t)j * NPTS] = fmaxf(oacc[nt][j] + bb2[j], 0.f);
        }
    }
}

extern "C" void kernel_launch(void* const* d_in, const int* in_sizes, int n_in,
                              void* d_out, int out_size, void* d_ws, size_t ws_size,
                              hipStream_t stream) {
    (void)in_sizes; (void)n_in; (void)out_size;
    const float* xyz1 = (const float*)d_in[0];
    const float* xyz2 = (const float*)d_in[1];
    const float* p1   = (const float*)d_in[2];
    const float* p2   = (const float*)d_in[3];
    const float* W1   = (const float*)d_in[4];
    const float* b1   = (const float*)d_in[5];
    const float* W2   = (const float*)d_in[6];
    const float* b2   = (const float*)d_in[7];
    float* out = (float*)d_out;

    dim3 grid(BBATCH * (NPTS / TN));   // 1024 blocks @ 2 resident/CU = 2 exact rounds
    dim3 block(512);
    if (ws_size >= (size_t)WS_F16_TOTAL * 2) {
        _Float16* ws = (_Float16*)d_ws;
        const int nswz = NFRAG_P2 + NFRAG_W1 + NFRAG_W2;   // 540672 = 2112 * 256
        cvt_swz<<<dim3(nswz / 256), dim3(256), 0, stream>>>(p2, W1, W2, ws);
        fp_mfma12<true><<<grid, block, 0, stream>>>(xyz1, xyz2, p1, p2, W1, b1, W2, b2,
                                                    ws + WS_P2S, ws + WS_W1S, ws + WS_W2S, out);
    } else {
        fp_mfma12<false><<<grid, block, 0, stream>>>(xyz1, xyz2, p1, p2, W1, b1, W2, b2,
                                                     nullptr, nullptr, nullptr, out);
    }
}

// Round 6
// 160.742 us; speedup vs baseline: 1.3471x; 1.0073x over previous
//
#include <hip/hip_runtime.h>
#include <math.h>

// Problem constants (from reference setup_inputs)
#define BBATCH 16
#define NPTS   4096
#define MPTS   1024
#define C1c    128
#define C2c    256
#define CINc   384
#define H1c    256
#define H2c    128
#define TN     64

typedef _Float16 f16x8 __attribute__((ext_vector_type(8)));
typedef _Float16 f16x4 __attribute__((ext_vector_type(4)));
typedef float    f32x4 __attribute__((ext_vector_type(4)));

// Raw barrier: drain LDS ops only; global prefetch loads stay in flight.
#define BAR() do { asm volatile("s_waitcnt lgkmcnt(0)" ::: "memory"); \
                   __builtin_amdgcn_s_barrier(); } while (0)

// ---- LDS layout (bytes) ---------------------------------------------------
// union [0,65536):
//   phase A: inv dbuf 2 x [8 cc][4 nt][64 lane][8 f16] = 2 x 32768 B
//            (256-m super-chunks: HALF the barrier events of R12's 128-m)
//   phase B: s_X frags [12 kc][4 nt][64][8] f16 = 49152 B
//   phase C: s_H frags [8 oc][4 nt][64][8] f16 = 32768 B
// s_xyz2 [1024][3] f32 = 12288 B at 65536 (outside union; dead after last gen)
// s_red 512 f32 at 77824
// Total 79872 B = 156*512 exact. 2 blocks/CU (159744 <= 163840), 16 waves/CU,
// grid 1024 = exactly 2 full rounds.
#define INV_HALF   16384           // f16 elems per inv buffer (32768 B)
#define OFF_XYZ2   65536
#define OFF_RED    77824
#define SMEM_BYTES 79872

// ---- fragment-swizzled workspace layout (f16 elements), unchanged ----
#define NFRAG_P2  (BBATCH * 32 * 16 * 64)        // 524288
#define NFRAG_W1  (16 * 12 * 64)                 // 12288
#define NFRAG_W2  (8 * 8 * 64)                   // 4096
#define WS_P2S  0
#define WS_W1S  (NFRAG_P2 * 8)                   // 4194304
#define WS_W2S  (WS_W1S + NFRAG_W1 * 8)
#define WS_F16_TOTAL (WS_W2S + NFRAG_W2 * 8)     // 4325376 f16 = 8650752 B

// ---------------------------------------------------------------------------
// pre-pass: convert + swizzle p2 / W1 / W2 into fragment-contiguous f16
__global__ __launch_bounds__(256) void cvt_swz(
    const float* __restrict__ p2, const float* __restrict__ W1,
    const float* __restrict__ W2, _Float16* __restrict__ ws)
{
    const int t = blockIdx.x * 256 + threadIdx.x;   // one fragment (8 f16) per thread
    const float* src;
    _Float16* dst;
    if (t < NFRAG_P2) {
        const int lane = t & 63, wt = (t >> 6) & 15, s = (t >> 10) & 31, b = t >> 15;
        const int c = wt * 16 + (lane & 15);
        const int m = s * 32 + (lane >> 4) * 8;
        src = p2 + ((size_t)(b * C2c + c)) * MPTS + m;
        dst = ws + WS_P2S + (size_t)t * 8;
    } else if (t < NFRAG_P2 + NFRAG_W1) {
        const int u = t - NFRAG_P2;
        const int lane = u & 63, kc = (u >> 6) % 12, wt = (u >> 6) / 12;
        const int o = wt * 16 + (lane & 15);
        const int k = kc * 32 + (lane >> 4) * 8;
        src = W1 + (size_t)o * CINc + k;
        dst = ws + WS_W1S + (size_t)u * 8;
    } else {
        const int v = t - NFRAG_P2 - NFRAG_W1;
        const int lane = v & 63, oc = (v >> 6) & 7, wt2 = v >> 9;
        const int o = wt2 * 16 + (lane & 15);
        const int k = oc * 32 + (lane >> 4) * 8;
        src = W2 + (size_t)o * H1c + k;
        dst = ws + WS_W2S + (size_t)v * 8;
    }
    const float4 a0 = *(const float4*)(src);
    const float4 a1 = *(const float4*)(src + 4);
    f16x8 h;
    h[0] = (_Float16)a0.x; h[1] = (_Float16)a0.y; h[2] = (_Float16)a0.z; h[3] = (_Float16)a0.w;
    h[4] = (_Float16)a1.x; h[5] = (_Float16)a1.y; h[6] = (_Float16)a1.z; h[7] = (_Float16)a1.w;
    *(f16x8*)dst = h;
}

// ---------------------------------------------------------------------------
// R13 = R12 with 256-m super-chunks: phase-A barrier events halve (8 -> 4).
// All resident waves stall together at each barrier (lockstep 8-wave blocks,
// co-resident blocks phase-aligned) — fewer, better-amortized barriers is the
// direct fix. gen mapping simplifies: wave w produces exactly sub-chunk cc=w
// (m = SS*256 + w*32 + g*8 + i -> frag cc=w, k-slot g, nt=quad, lane l16).
// Ring-4 distance-2 A-prefetch, peeled-last-chunk p1 overlap, raw lgkm-only
// barriers, frag layouts, (512,4) no-spill regime: unchanged from R12.
template <bool F16P>
__global__ __launch_bounds__(512, 4) void fp_mfma13(
    const float* __restrict__ xyz1, const float* __restrict__ xyz2,
    const float* __restrict__ p1,   const float* __restrict__ p2,
    const float* __restrict__ W1,   const float* __restrict__ b1v,
    const float* __restrict__ W2,   const float* __restrict__ b2v,
    const _Float16* __restrict__ p2s, const _Float16* __restrict__ W1s,
    const _Float16* __restrict__ W2s,
    float* __restrict__ out)
{
    __shared__ __align__(16) char smem[SMEM_BYTES];
    _Float16* s_inv  = (_Float16*)smem;
    _Float16* s_X    = (_Float16*)smem;
    _Float16* s_H    = (_Float16*)smem;
    float*    s_xyz2 = (float*)(smem + OFF_XYZ2);
    float*    s_red  = (float*)(smem + OFF_RED);

    const int tid  = threadIdx.x;
    const int w    = tid >> 6;    // wave 0..7
    const int L    = tid & 63;
    const int quad = L >> 4;
    const int l16  = L & 15;

    // XCD swizzle: each XCD sees 2 batches -> p2s working set (1 MB) L2-resident
    const int id = blockIdx.x;            // 1024 blocks
    const int b  = (id & 7) * 2 + ((id >> 3) & 1);
    const int n0 = (id >> 4) * TN;

    const float* __restrict__ z2b = xyz2 + (size_t)b * MPTS * 3;
    const float* __restrict__ p2b = p2   + (size_t)b * C2c * MPTS;
    const _Float16* __restrict__ p2sb =
        F16P ? (p2s + (((size_t)b * 32 * 16 + (size_t)w * 2) * 64 + L) * 8) : (const _Float16*)nullptr;

    // stage xyz2 (12 KB, coalesced f32x4)
    for (int i = tid; i < MPTS * 3 / 4; i += 512)
        ((f32x4*)s_xyz2)[i] = ((const f32x4*)z2b)[i];

    const float x1x = xyz1[((size_t)b * NPTS + n0 + L) * 3 + 0];
    const float x1y = xyz1[((size_t)b * NPTS + n0 + L) * 3 + 1];
    const float x1z = xyz1[((size_t)b * NPTS + n0 + L) * 3 + 2];

    f32x4 acc[2][4];   // [ct][nt]: row c = w*32+ct*16+quad*4+r, col n = nt*16+l16
    #pragma unroll
    for (int ct = 0; ct < 2; ++ct)
        #pragma unroll
        for (int nt = 0; nt < 4; ++nt)
            acc[ct][nt] = (f32x4){0.f, 0.f, 0.f, 0.f};

    float ssum0 = 0.f, ssum1 = 0.f;   // dual accumulators (dep-chain relief)
    f16x8 Aa[4][2];    // A-frag ring, slot = chunk & 3 (prefetch distance 2)

    auto loadA = [&](int s, f16x8 dst[2]) {
        if (F16P) {
            const _Float16* ap = p2sb + (size_t)s * (16 * 64 * 8);
            #pragma unroll
            for (int ct = 0; ct < 2; ++ct)
                dst[ct] = *(const f16x8*)(ap + (size_t)ct * (64 * 8));
        } else {
            const float* ap = p2b + (size_t)(w * 32 + l16) * MPTS + s * 32 + quad * 8;
            #pragma unroll
            for (int ct = 0; ct < 2; ++ct) {
                const float4 a0 = *(const float4*)(ap + (size_t)ct * (16 * MPTS));
                const float4 a1 = *(const float4*)(ap + (size_t)ct * (16 * MPTS) + 4);
                f16x8 h;
                h[0] = (_Float16)a0.x; h[1] = (_Float16)a0.y; h[2] = (_Float16)a0.z; h[3] = (_Float16)a0.w;
                h[4] = (_Float16)a1.x; h[5] = (_Float16)a1.y; h[6] = (_Float16)a1.z; h[7] = (_Float16)a1.w;
                dst[ct] = h;
            }
        }
    };

    // one 8-m group of 256-m super-chunk SS into frag buffer (SS&1), g in 0..3:
    // thread (w,L): n=L, m = SS*256 + w*32 + g*8 + i
    //   -> frag cc = w, k-slot g, nt = quad, lane l16. One dense f16x8 store.
    auto gen_g = [&](int SS_, int g) {
        _Float16* buf = s_inv + (SS_ & 1) * INV_HALF;
        const float* zp = s_xyz2 + (size_t)(SS_ * 256 + w * 32 + g * 8) * 3;
        f32x4 zr[6];
        #pragma unroll
        for (int j = 0; j < 6; ++j) zr[j] = ((const f32x4*)zp)[j];
        const float* zv = (const float*)zr;
        f16x8 iv;
        #pragma unroll
        for (int i = 0; i < 8; ++i) {
            const float dx = x1x - zv[3 * i + 0];
            const float dy = x1y - zv[3 * i + 1];
            const float dz = x1z - zv[3 * i + 2];
            const float d2 = fmaf(dx, dx, fmaf(dy, dy, fmaf(dz, dz, 1e-12f)));
            const float inv = __builtin_amdgcn_rsqf(d2);
            if (i & 1) ssum1 += inv; else ssum0 += inv;
            iv[i] = (_Float16)inv;
        }
        *(f16x8*)(buf + (((w * 4 + quad) * 64) + g * 16 + l16) * 8) = iv;
    };

    loadA(0, Aa[0]);
    loadA(1, Aa[1]);
    BAR();             // xyz2 staged (lgkm drain; A-prefetch stays in flight)
    #pragma unroll
    for (int g = 0; g < 4; ++g) gen_g(0, g);
    BAR();             // super-chunk 0 visible

    // ---- main phase-A loop: SS = 0..2 (SS = 3 peeled below) ----
    for (int SS = 0; SS < 3; ++SS) {
        const _Float16* buf = s_inv + (SS & 1) * INV_HALF;
        #pragma unroll
        for (int cc = 0; cc < 8; ++cc) {
            const int s = SS * 8 + cc;
            loadA(s + 2, Aa[(cc + 2) & 3]);        // distance-2 ring (s+2 <= 25)
            if ((cc & 1) == 0) gen_g(SS + 1, cc >> 1);   // 4 gens over 8 steps
            __builtin_amdgcn_s_setprio(1);
            #pragma unroll
            for (int nt = 0; nt < 4; ++nt) {
                const f16x8 bf = *(const f16x8*)(buf + ((cc * 4 + nt) * 64 + L) * 8);
                #pragma unroll
                for (int ct = 0; ct < 2; ++ct)
                    acc[ct][nt] = __builtin_amdgcn_mfma_f32_16x16x32_f16(Aa[cc & 3][ct], bf, acc[ct][nt], 0, 0, 0);
            }
            __builtin_amdgcn_s_setprio(0);
        }
        BAR();   // reads of buf(SS) done; writes of buf(SS+1) done; vm loads live
    }

    // ---- peeled SS = 3: p1 loads issued first, hidden under the MFMAs ----
    float tv[2][8];
    {
        #pragma unroll
        for (int h = 0; h < 2; ++h) {
            const int f  = w * 2 + h;      // 0..15
            const int kq = f >> 2, nt = f & 3;
            const float* pp = p1 + ((size_t)b * C1c + kq * 32 + quad * 8) * NPTS + n0 + nt * 16 + l16;
            #pragma unroll
            for (int j = 0; j < 8; ++j) tv[h][j] = pp[(size_t)j * NPTS];
        }
    }
    {
        const _Float16* buf = s_inv + INV_HALF;   // 3 & 1 = 1
        #pragma unroll
        for (int cc = 0; cc < 8; ++cc) {
            if (cc < 6) loadA(26 + cc, Aa[(cc + 2) & 3]);   // chunks 26..31
            __builtin_amdgcn_s_setprio(1);
            #pragma unroll
            for (int nt = 0; nt < 4; ++nt) {
                const f16x8 bf = *(const f16x8*)(buf + ((cc * 4 + nt) * 64 + L) * 8);
                #pragma unroll
                for (int ct = 0; ct < 2; ++ct)
                    acc[ct][nt] = __builtin_amdgcn_mfma_f32_16x16x32_f16(Aa[cc & 3][ct], bf, acc[ct][nt], 0, 0, 0);
            }
            __builtin_amdgcn_s_setprio(0);
        }
    }
    // p1 -> s_X frags kq 0..3 (bytes [0,16K) = buf0 lower half; buf0's last
    // reads were SS=2, drained at that barrier). s_red is outside the union.
    {
        #pragma unroll
        for (int h = 0; h < 2; ++h) {
            const int f = w * 2 + h;
            f16x8 v;
            #pragma unroll
            for (int j = 0; j < 8; ++j) v[j] = (_Float16)tv[h][j];
            *(f16x8*)(s_X + ((size_t)f * 64 + L) * 8) = v;
        }
    }
    s_red[tid] = ssum0 + ssum1;
    BAR();

    // ---- recip over the 8 m-slice partials
    if (tid < 64) {
        float s = 0.f;
        #pragma unroll
        for (int wv = 0; wv < 8; ++wv) s += s_red[wv * 64 + tid];
        s_red[tid] = 1.0f / s;
    }
    BAR();   // recip ready; phase-A scratch dead -> interp overlay safe

    // phase-B prefetch issued now: flies across the interp work + barrier
    f16x8 afP[2][2];
    auto loadW1 = [&](int kc, f16x8 dst[2]) {
        if (F16P) {
            const _Float16* wp = W1s + (((size_t)(w * 2) * 12 + kc) * 64 + L) * 8;
            #pragma unroll
            for (int ct = 0; ct < 2; ++ct)
                dst[ct] = *(const f16x8*)(wp + (size_t)ct * (12 * 64 * 8));
        } else {
            const float* wp = W1 + (size_t)(w * 32 + l16) * CINc + kc * 32 + quad * 8;
            #pragma unroll
            for (int ct = 0; ct < 2; ++ct) {
                const float4 a0 = *(const float4*)(wp + ct * (16 * CINc));
                const float4 a1 = *(const float4*)(wp + ct * (16 * CINc) + 4);
                f16x8 h;
                h[0] = (_Float16)a0.x; h[1] = (_Float16)a0.y; h[2] = (_Float16)a0.z; h[3] = (_Float16)a0.w;
                h[4] = (_Float16)a1.x; h[5] = (_Float16)a1.y; h[6] = (_Float16)a1.z; h[7] = (_Float16)a1.w;
                dst[ct] = h;
            }
        }
    };
    loadW1(0, afP[0]);

    // interp -> s_X frags kq = 4 + w (bytes [16K,48K): buf0-upper dead since
    // SS=2 barrier; buf1-lower reads (SS=3) drained at the post-ssum barrier).
    {
        float rn4[4];
        #pragma unroll
        for (int nt = 0; nt < 4; ++nt) rn4[nt] = s_red[nt * 16 + l16];
        #pragma unroll
        for (int ct = 0; ct < 2; ++ct) {
            const int kq = 4 + w;
            const int lp = (ct * 2 + (quad >> 1)) * 16 + l16;
            const int jo = (quad & 1) * 4;
            #pragma unroll
            for (int nt = 0; nt < 4; ++nt) {
                const f32x4 v = acc[ct][nt];
                const float r = rn4[nt];
                f16x4 hv;
                hv[0] = (_Float16)(v[0] * r);
                hv[1] = (_Float16)(v[1] * r);
                hv[2] = (_Float16)(v[2] * r);
                hv[3] = (_Float16)(v[3] * r);
                *(f16x4*)(s_X + (((size_t)(kq * 4 + nt)) * 64 + lp) * 8 + jo) = hv;
            }
        }
    }
    BAR();   // full X (p1 + interp) frags complete; W1 frag-0 still in flight

    // ---------------- Phase B: h = relu(W1 @ X + b1), K=384 ----------------
    f32x4 hacc[2][4];
    #pragma unroll
    for (int ct = 0; ct < 2; ++ct)
        #pragma unroll
        for (int nt = 0; nt < 4; ++nt)
            hacc[ct][nt] = (f32x4){0.f, 0.f, 0.f, 0.f};

    #pragma unroll
    for (int kc = 0; kc < 12; ++kc) {
        if (kc + 1 < 12) loadW1(kc + 1, afP[(kc + 1) & 1]);
        __builtin_amdgcn_s_setprio(1);
        #pragma unroll
        for (int nt = 0; nt < 4; ++nt) {
            const f16x8 bf = *(const f16x8*)(s_X + (((size_t)(kc * 4 + nt)) * 64 + L) * 8);
            #pragma unroll
            for (int ct = 0; ct < 2; ++ct)
                hacc[ct][nt] = __builtin_amdgcn_mfma_f32_16x16x32_f16(afP[kc & 1][ct], bf, hacc[ct][nt], 0, 0, 0);
        }
        __builtin_amdgcn_s_setprio(0);
    }

    BAR();   // all s_X reads done before overlaying s_H

    // phase-C prefetch issued now: flies across h-stage + barrier
    f16x8 afP2[2];
    auto loadW2 = [&](int oc, f16x8& dst) {
        if (F16P) {
            dst = *(const f16x8*)(W2s + (((size_t)(w * 8 + oc)) * 64 + L) * 8);
        } else {
            const float* wp = W2 + (size_t)(w * 16 + l16) * H1c + oc * 32 + quad * 8;
            const float4 a0 = *(const float4*)(wp);
            const float4 a1 = *(const float4*)(wp + 4);
            f16x8 h;
            h[0] = (_Float16)a0.x; h[1] = (_Float16)a0.y; h[2] = (_Float16)a0.z; h[3] = (_Float16)a0.w;
            h[4] = (_Float16)a1.x; h[5] = (_Float16)a1.y; h[6] = (_Float16)a1.z; h[7] = (_Float16)a1.w;
            dst = h;
        }
    };
    loadW2(0, afP2[0]);

    // bias + relu + stage h -> s_H frag layout (oq = w, same slot math as interp)
    {
        f32x4 bb[2];
        #pragma unroll
        for (int ct = 0; ct < 2; ++ct)
            bb[ct] = *(const f32x4*)(b1v + w * 32 + ct * 16 + quad * 4);
        #pragma unroll
        for (int ct = 0; ct < 2; ++ct) {
            const int lp = (ct * 2 + (quad >> 1)) * 16 + l16;
            const int jo = (quad & 1) * 4;
            #pragma unroll
            for (int nt = 0; nt < 4; ++nt) {
                const f32x4 v = hacc[ct][nt];
                f16x4 hv;
                hv[0] = (_Float16)fmaxf(v[0] + bb[ct][0], 0.f);
                hv[1] = (_Float16)fmaxf(v[1] + bb[ct][1], 0.f);
                hv[2] = (_Float16)fmaxf(v[2] + bb[ct][2], 0.f);
                hv[3] = (_Float16)fmaxf(v[3] + bb[ct][3], 0.f);
                *(f16x4*)(s_H + (((size_t)(w * 4 + nt)) * 64 + lp) * 8 + jo) = hv;
            }
        }
    }
    BAR();

    // ---------------- Phase C: out = relu(W2 @ h + b2), K=256 --------------
    f32x4 oacc[4];
    #pragma unroll
    for (int nt = 0; nt < 4; ++nt)
        oacc[nt] = (f32x4){0.f, 0.f, 0.f, 0.f};

    #pragma unroll
    for (int oc = 0; oc < 8; ++oc) {
        if (oc + 1 < 8) loadW2(oc + 1, afP2[(oc + 1) & 1]);
        __builtin_amdgcn_s_setprio(1);
        #pragma unroll
        for (int nt = 0; nt < 4; ++nt) {
            const f16x8 bf = *(const f16x8*)(s_H + (((size_t)(oc * 4 + nt)) * 64 + L) * 8);
            oacc[nt] = __builtin_amdgcn_mfma_f32_16x16x32_f16(afP2[oc & 1], bf, oacc[nt], 0, 0, 0);
        }
        __builtin_amdgcn_s_setprio(0);
    }

    // epilogue: bias + relu + store (o = w*16 + quad*4 + j)
    {
        const f32x4 bb2 = *(const f32x4*)(b2v + w * 16 + quad * 4);
        #pragma unroll
        for (int nt = 0; nt < 4; ++nt) {
            float* op = out + ((size_t)b * H2c + w * 16 + quad * 4) * NPTS
                            + n0 + nt * 16 + l16;
            #pragma unroll
            for (int j = 0; j < 4; ++j)
                op[(size_t)j * NPTS] = fmaxf(oacc[nt][j] + bb2[j], 0.f);
        }
    }
}

extern "C" void kernel_launch(void* const* d_in, const int* in_sizes, int n_in,
                              void* d_out, int out_size, void* d_ws, size_t ws_size,
                              hipStream_t stream) {
    (void)in_sizes; (void)n_in; (void)out_size;
    const float* xyz1 = (const float*)d_in[0];
    const float* xyz2 = (const float*)d_in[1];
    const float* p1   = (const float*)d_in[2];
    const float* p2   = (const float*)d_in[3];
    const float* W1   = (const float*)d_in[4];
    const float* b1   = (const float*)d_in[5];
    const float* W2   = (const float*)d_in[6];
    const float* b2   = (const float*)d_in[7];
    float* out = (float*)d_out;

    dim3 grid(BBATCH * (NPTS / TN));   // 1024 blocks @ 2 resident/CU = 2 exact rounds
    dim3 block(512);
    if (ws_size >= (size_t)WS_F16_TOTAL * 2) {
        _Float16* ws = (_Float16*)d_ws;
        const int nswz = NFRAG_P2 + NFRAG_W1 + NFRAG_W2;   // 540672 = 2112 * 256
        cvt_swz<<<dim3(nswz / 256), dim3(256), 0, stream>>>(p2, W1, W2, ws);
        fp_mfma13<true><<<grid, block, 0, stream>>>(xyz1, xyz2, p1, p2, W1, b1, W2, b2,
                                                    ws + WS_P2S, ws + WS_W1S, ws + WS_W2S, out);
    } else {
        fp_mfma13<false><<<grid, block, 0, stream>>>(xyz1, xyz2, p1, p2, W1, b1, W2, b2,
                                                     nullptr, nullptr, nullptr, out);
    }
}

// Round 7
// 159.790 us; speedup vs baseline: 1.3551x; 1.0060x over previous
//
#include <hip/hip_runtime.h>
#include <math.h>

// Problem constants (from reference setup_inputs)
#define BBATCH 16
#define NPTS   4096
#define MPTS   1024
#define C1c    128
#define C2c    256
#define CINc   384
#define H1c    256
#define H2c    128
#define TN     64

typedef _Float16 f16x8 __attribute__((ext_vector_type(8)));
typedef _Float16 f16x4 __attribute__((ext_vector_type(4)));
typedef float    f32x4 __attribute__((ext_vector_type(4)));

// Raw barrier: drain LDS ops only; global prefetch loads stay in flight.
#define BAR() do { asm volatile("s_waitcnt lgkmcnt(0)" ::: "memory"); \
                   __builtin_amdgcn_s_barrier(); } while (0)

// ---- LDS layout (bytes) ---------------------------------------------------
// union [0,49152):
//   phase A: inv dbuf 2 x [4 cc][4 nt][64 lane][8 f16] = 32768 B
//            s_xyz2 [1024][3] f32 = 12288 B at 32768 (dead after last gen)
//   phase B: s_X frags [12 kc][4 nt][64][8] f16 = 49152 B
//   phase C: s_H frags [8 oc][4 nt][64][8] f16 = 32768 B
// s_red 512 f32 at 49152 (recip overlaid in first 64)
// Total 51200 B -> 3 blocks/CU (153.6 KB <= 160 KB) with the 64-reg class:
// 24 waves/CU = 6 waves/SIMD. R11-R13 all sat at 2 blocks/CU (4 waves/SIMD)
// and were latency-bound with correlated stalls; this is the residency fix.
#define INV_HALF   8192            // f16 elems per inv buffer (16384 B)
#define OFF_XYZ2   32768
#define OFF_RED    49152
#define SMEM_BYTES 51200

// ---- fragment-swizzled workspace layout (f16 elements), unchanged ----
#define NFRAG_P2  (BBATCH * 32 * 16 * 64)        // 524288
#define NFRAG_W1  (16 * 12 * 64)                 // 12288
#define NFRAG_W2  (8 * 8 * 64)                   // 4096
#define WS_P2S  0
#define WS_W1S  (NFRAG_P2 * 8)                   // 4194304
#define WS_W2S  (WS_W1S + NFRAG_W1 * 8)
#define WS_F16_TOTAL (WS_W2S + NFRAG_W2 * 8)     // 4325376 f16 = 8650752 B

// ---------------------------------------------------------------------------
// pre-pass: convert + swizzle p2 / W1 / W2 into fragment-contiguous f16
__global__ __launch_bounds__(256) void cvt_swz(
    const float* __restrict__ p2, const float* __restrict__ W1,
    const float* __restrict__ W2, _Float16* __restrict__ ws)
{
    const int t = blockIdx.x * 256 + threadIdx.x;   // one fragment (8 f16) per thread
    const float* src;
    _Float16* dst;
    if (t < NFRAG_P2) {
        const int lane = t & 63, wt = (t >> 6) & 15, s = (t >> 10) & 31, b = t >> 15;
        const int c = wt * 16 + (lane & 15);
        const int m = s * 32 + (lane >> 4) * 8;
        src = p2 + ((size_t)(b * C2c + c)) * MPTS + m;
        dst = ws + WS_P2S + (size_t)t * 8;
    } else if (t < NFRAG_P2 + NFRAG_W1) {
        const int u = t - NFRAG_P2;
        const int lane = u & 63, kc = (u >> 6) % 12, wt = (u >> 6) / 12;
        const int o = wt * 16 + (lane & 15);
        const int k = kc * 32 + (lane >> 4) * 8;
        src = W1 + (size_t)o * CINc + k;
        dst = ws + WS_W1S + (size_t)u * 8;
    } else {
        const int v = t - NFRAG_P2 - NFRAG_W1;
        const int lane = v & 63, oc = (v >> 6) & 7, wt2 = v >> 9;
        const int o = wt2 * 16 + (lane & 15);
        const int k = oc * 32 + (lane >> 4) * 8;
        src = W2 + (size_t)o * H1c + k;
        dst = ws + WS_W2S + (size_t)v * 8;
    }
    const float4 a0 = *(const float4*)(src);
    const float4 a1 = *(const float4*)(src + 4);
    f16x8 h;
    h[0] = (_Float16)a0.x; h[1] = (_Float16)a0.y; h[2] = (_Float16)a0.z; h[3] = (_Float16)a0.w;
    h[4] = (_Float16)a1.x; h[5] = (_Float16)a1.y; h[6] = (_Float16)a1.z; h[7] = (_Float16)a1.w;
    *(f16x8*)dst = h;
}

// ---------------------------------------------------------------------------
// R14 = R12 with __launch_bounds__(512, 8): forces the 64-VGPR class (R12
// naturally used 52), making residency LDS-limited at 3 blocks/CU instead of
// the bounds-implied 2. 24 waves/CU = 6 waves/SIMD, and the 3rd block is
// phase-decorrelated from the other two (fills their barrier/latency windows).
// Dataflow, frag layouts, ring-4 distance-2 A-prefetch, peeled-p1 overlap,
// lgkm-only raw barriers: identical to R12 (R13's 256-m chunks reverted —
// neutral, and their LDS growth would forbid the 3rd block).
template <bool F16P>
__global__ __launch_bounds__(512, 8) void fp_mfma14(
    const float* __restrict__ xyz1, const float* __restrict__ xyz2,
    const float* __restrict__ p1,   const float* __restrict__ p2,
    const float* __restrict__ W1,   const float* __restrict__ b1v,
    const float* __restrict__ W2,   const float* __restrict__ b2v,
    const _Float16* __restrict__ p2s, const _Float16* __restrict__ W1s,
    const _Float16* __restrict__ W2s,
    float* __restrict__ out)
{
    __shared__ __align__(16) char smem[SMEM_BYTES];
    _Float16* s_inv  = (_Float16*)smem;
    _Float16* s_X    = (_Float16*)smem;
    _Float16* s_H    = (_Float16*)smem;
    float*    s_xyz2 = (float*)(smem + OFF_XYZ2);
    float*    s_red  = (float*)(smem + OFF_RED);

    const int tid  = threadIdx.x;
    const int w    = tid >> 6;    // wave 0..7
    const int L    = tid & 63;
    const int quad = L >> 4;
    const int l16  = L & 15;

    // XCD swizzle: each XCD sees 2 batches -> p2s working set (1 MB) L2-resident
    const int id = blockIdx.x;            // 1024 blocks
    const int b  = (id & 7) * 2 + ((id >> 3) & 1);
    const int n0 = (id >> 4) * TN;

    const float* __restrict__ z2b = xyz2 + (size_t)b * MPTS * 3;
    const float* __restrict__ p2b = p2   + (size_t)b * C2c * MPTS;
    const _Float16* __restrict__ p2sb =
        F16P ? (p2s + (((size_t)b * 32 * 16 + (size_t)w * 2) * 64 + L) * 8) : (const _Float16*)nullptr;

    // stage xyz2 (12 KB, coalesced f32x4)
    for (int i = tid; i < MPTS * 3 / 4; i += 512)
        ((f32x4*)s_xyz2)[i] = ((const f32x4*)z2b)[i];

    const float x1x = xyz1[((size_t)b * NPTS + n0 + L) * 3 + 0];
    const float x1y = xyz1[((size_t)b * NPTS + n0 + L) * 3 + 1];
    const float x1z = xyz1[((size_t)b * NPTS + n0 + L) * 3 + 2];

    f32x4 acc[2][4];   // [ct][nt]: row c = w*32+ct*16+quad*4+r, col n = nt*16+l16
    #pragma unroll
    for (int ct = 0; ct < 2; ++ct)
        #pragma unroll
        for (int nt = 0; nt < 4; ++nt)
            acc[ct][nt] = (f32x4){0.f, 0.f, 0.f, 0.f};

    float ssum = 0.f;
    f16x8 Aa[4][2];    // A-frag ring, slot = chunk & 3 (prefetch distance 2)

    auto loadA = [&](int s, f16x8 dst[2]) {
        if (F16P) {
            const _Float16* ap = p2sb + (size_t)s * (16 * 64 * 8);
            #pragma unroll
            for (int ct = 0; ct < 2; ++ct)
                dst[ct] = *(const f16x8*)(ap + (size_t)ct * (64 * 8));
        } else {
            const float* ap = p2b + (size_t)(w * 32 + l16) * MPTS + s * 32 + quad * 8;
            #pragma unroll
            for (int ct = 0; ct < 2; ++ct) {
                const float4 a0 = *(const float4*)(ap + (size_t)ct * (16 * MPTS));
                const float4 a1 = *(const float4*)(ap + (size_t)ct * (16 * MPTS) + 4);
                f16x8 h;
                h[0] = (_Float16)a0.x; h[1] = (_Float16)a0.y; h[2] = (_Float16)a0.z; h[3] = (_Float16)a0.w;
                h[4] = (_Float16)a1.x; h[5] = (_Float16)a1.y; h[6] = (_Float16)a1.z; h[7] = (_Float16)a1.w;
                dst[ct] = h;
            }
        }
    };

    // one 8-m group of super-chunk ss_ into frag buffer (ss_&1), g in {0,1}:
    // thread (w,L): n=L, m = ss_*128 + w*16 + g*8 + i
    //   -> frag (cc = w>>1, nt = quad), k-slot q' = (w&1)*2+g, lane l16.
    auto gen_g = [&](int ss_, int g) {
        _Float16* buf = s_inv + (ss_ & 1) * INV_HALF;
        const float* zp = s_xyz2 + (size_t)(ss_ * 128 + w * 16 + g * 8) * 3;
        f32x4 zr[6];
        #pragma unroll
        for (int j = 0; j < 6; ++j) zr[j] = ((const f32x4*)zp)[j];
        const float* zv = (const float*)zr;
        f16x8 iv;
        #pragma unroll
        for (int i = 0; i < 8; ++i) {
            const float dx = x1x - zv[3 * i + 0];
            const float dy = x1y - zv[3 * i + 1];
            const float dz = x1z - zv[3 * i + 2];
            const float d2 = fmaf(dx, dx, fmaf(dy, dy, fmaf(dz, dz, 1e-12f)));
            const float inv = __builtin_amdgcn_rsqf(d2);
            ssum += inv;
            iv[i] = (_Float16)inv;
        }
        *(f16x8*)(buf + ((((w >> 1) * 4 + quad) * 64) + ((w & 1) * 2 + g) * 16 + l16) * 8) = iv;
    };

    loadA(0, Aa[0]);
    loadA(1, Aa[1]);
    BAR();             // xyz2 staged (lgkm drain; A-prefetch stays in flight)
    gen_g(0, 0);
    gen_g(0, 1);
    BAR();             // super-chunk 0 visible

    // ---- main phase-A loop: ss = 0..6 (ss = 7 peeled below) ----
    for (int ss = 0; ss < 7; ++ss) {
        const _Float16* buf = s_inv + (ss & 1) * INV_HALF;
        #pragma unroll
        for (int cc = 0; cc < 4; ++cc) {
            const int s = ss * 4 + cc;
            loadA(s + 2, Aa[(cc + 2) & 3]);   // distance-2 ring prefetch (s+2 <= 29)
            if (cc < 2) gen_g(ss + 1, cc);    // inv VALU interleaved
            __builtin_amdgcn_s_setprio(1);
            #pragma unroll
            for (int nt = 0; nt < 4; ++nt) {
                const f16x8 bf = *(const f16x8*)(buf + ((cc * 4 + nt) * 64 + L) * 8);
                #pragma unroll
                for (int ct = 0; ct < 2; ++ct)
                    acc[ct][nt] = __builtin_amdgcn_mfma_f32_16x16x32_f16(Aa[cc][ct], bf, acc[ct][nt], 0, 0, 0);
            }
            __builtin_amdgcn_s_setprio(0);
        }
        BAR();   // reads of buf(ss) done; writes of buf(ss+1) done; vm loads live
    }

    // ---- peeled ss = 7: p1 loads issued first, hidden under the MFMAs ----
    float tv[2][8];
    {
        #pragma unroll
        for (int h = 0; h < 2; ++h) {
            const int f  = w * 2 + h;      // 0..15
            const int kq = f >> 2, nt = f & 3;
            const float* pp = p1 + ((size_t)b * C1c + kq * 32 + quad * 8) * NPTS + n0 + nt * 16 + l16;
            #pragma unroll
            for (int j = 0; j < 8; ++j) tv[h][j] = pp[(size_t)j * NPTS];
        }
    }
    {
        const _Float16* buf = s_inv + INV_HALF;   // 7 & 1 = 1
        #pragma unroll
        for (int cc = 0; cc < 4; ++cc) {
            if (cc < 2) loadA(28 + cc + 2, Aa[(cc + 2) & 3]);   // chunks 30, 31
            __builtin_amdgcn_s_setprio(1);
            #pragma unroll
            for (int nt = 0; nt < 4; ++nt) {
                const f16x8 bf = *(const f16x8*)(buf + ((cc * 4 + nt) * 64 + L) * 8);
                #pragma unroll
                for (int ct = 0; ct < 2; ++ct)
                    acc[ct][nt] = __builtin_amdgcn_mfma_f32_16x16x32_f16(Aa[cc][ct], bf, acc[ct][nt], 0, 0, 0);
            }
            __builtin_amdgcn_s_setprio(0);
        }
    }
    // p1 -> s_X frags kq 0..3 (bytes [0,16K) = buf0; its last reads were ss=6,
    // drained at that barrier). ssum store: s_red is outside the union.
    {
        #pragma unroll
        for (int h = 0; h < 2; ++h) {
            const int f = w * 2 + h;
            f16x8 v;
            #pragma unroll
            for (int j = 0; j < 8; ++j) v[j] = (_Float16)tv[h][j];
            *(f16x8*)(s_X + ((size_t)f * 64 + L) * 8) = v;
        }
    }
    s_red[tid] = ssum;
    BAR();

    // ---- recip over the 8 m-slice partials
    if (tid < 64) {
        float s = 0.f;
        #pragma unroll
        for (int wv = 0; wv < 8; ++wv) s += s_red[wv * 64 + tid];
        s_red[tid] = 1.0f / s;
    }
    BAR();   // recip ready; phase-A scratch dead -> interp overlay safe

    // phase-B prefetch issued now: flies across the interp work + barrier
    f16x8 afP[2][2];
    auto loadW1 = [&](int kc, f16x8 dst[2]) {
        if (F16P) {
            const _Float16* wp = W1s + (((size_t)(w * 2) * 12 + kc) * 64 + L) * 8;
            #pragma unroll
            for (int ct = 0; ct < 2; ++ct)
                dst[ct] = *(const f16x8*)(wp + (size_t)ct * (12 * 64 * 8));
        } else {
            const float* wp = W1 + (size_t)(w * 32 + l16) * CINc + kc * 32 + quad * 8;
            #pragma unroll
            for (int ct = 0; ct < 2; ++ct) {
                const float4 a0 = *(const float4*)(wp + ct * (16 * CINc));
                const float4 a1 = *(const float4*)(wp + ct * (16 * CINc) + 4);
                f16x8 h;
                h[0] = (_Float16)a0.x; h[1] = (_Float16)a0.y; h[2] = (_Float16)a0.z; h[3] = (_Float16)a0.w;
                h[4] = (_Float16)a1.x; h[5] = (_Float16)a1.y; h[6] = (_Float16)a1.z; h[7] = (_Float16)a1.w;
                dst[ct] = h;
            }
        }
    };
    loadW1(0, afP[0]);

    // interp -> s_X frags kq = 4 + w (bytes [16K,48K): dead buf1 + dead xyz2).
    {
        float rn4[4];
        #pragma unroll
        for (int nt = 0; nt < 4; ++nt) rn4[nt] = s_red[nt * 16 + l16];
        #pragma unroll
        for (int ct = 0; ct < 2; ++ct) {
            const int kq = 4 + w;
            const int lp = (ct * 2 + (quad >> 1)) * 16 + l16;
            const int jo = (quad & 1) * 4;
            #pragma unroll
            for (int nt = 0; nt < 4; ++nt) {
                const f32x4 v = acc[ct][nt];
                const float r = rn4[nt];
                f16x4 hv;
                hv[0] = (_Float16)(v[0] * r);
                hv[1] = (_Float16)(v[1] * r);
                hv[2] = (_Float16)(v[2] * r);
                hv[3] = (_Float16)(v[3] * r);
                *(f16x4*)(s_X + (((size_t)(kq * 4 + nt)) * 64 + lp) * 8 + jo) = hv;
            }
        }
    }
    BAR();   // full X (p1 + interp) frags complete; W1 frag-0 still in flight

    // ---------------- Phase B: h = relu(W1 @ X + b1), K=384 ----------------
    f32x4 hacc[2][4];
    #pragma unroll
    for (int ct = 0; ct < 2; ++ct)
        #pragma unroll
        for (int nt = 0; nt < 4; ++nt)
            hacc[ct][nt] = (f32x4){0.f, 0.f, 0.f, 0.f};

    #pragma unroll
    for (int kc = 0; kc < 12; ++kc) {
        if (kc + 1 < 12) loadW1(kc + 1, afP[(kc + 1) & 1]);
        __builtin_amdgcn_s_setprio(1);
        #pragma unroll
        for (int nt = 0; nt < 4; ++nt) {
            const f16x8 bf = *(const f16x8*)(s_X + (((size_t)(kc * 4 + nt)) * 64 + L) * 8);
            #pragma unroll
            for (int ct = 0; ct < 2; ++ct)
                hacc[ct][nt] = __builtin_amdgcn_mfma_f32_16x16x32_f16(afP[kc & 1][ct], bf, hacc[ct][nt], 0, 0, 0);
        }
        __builtin_amdgcn_s_setprio(0);
    }

    BAR();   // all s_X reads done before overlaying s_H

    // phase-C prefetch issued now: flies across h-stage + barrier
    f16x8 afP2[2];
    auto loadW2 = [&](int oc, f16x8& dst) {
        if (F16P) {
            dst = *(const f16x8*)(W2s + (((size_t)(w * 8 + oc)) * 64 + L) * 8);
        } else {
            const float* wp = W2 + (size_t)(w * 16 + l16) * H1c + oc * 32 + quad * 8;
            const float4 a0 = *(const float4*)(wp);
            const float4 a1 = *(const float4*)(wp + 4);
            f16x8 h;
            h[0] = (_Float16)a0.x; h[1] = (_Float16)a0.y; h[2] = (_Float16)a0.z; h[3] = (_Float16)a0.w;
            h[4] = (_Float16)a1.x; h[5] = (_Float16)a1.y; h[6] = (_Float16)a1.z; h[7] = (_Float16)a1.w;
            dst = h;
        }
    };
    loadW2(0, afP2[0]);

    // bias + relu + stage h -> s_H frag layout (oq = w, same slot math as interp)
    {
        f32x4 bb[2];
        #pragma unroll
        for (int ct = 0; ct < 2; ++ct)
            bb[ct] = *(const f32x4*)(b1v + w * 32 + ct * 16 + quad * 4);
        #pragma unroll
        for (int ct = 0; ct < 2; ++ct) {
            const int lp = (ct * 2 + (quad >> 1)) * 16 + l16;
            const int jo = (quad & 1) * 4;
            #pragma unroll
            for (int nt = 0; nt < 4; ++nt) {
                const f32x4 v = hacc[ct][nt];
                f16x4 hv;
                hv[0] = (_Float16)fmaxf(v[0] + bb[ct][0], 0.f);
                hv[1] = (_Float16)fmaxf(v[1] + bb[ct][1], 0.f);
                hv[2] = (_Float16)fmaxf(v[2] + bb[ct][2], 0.f);
                hv[3] = (_Float16)fmaxf(v[3] + bb[ct][3], 0.f);
                *(f16x4*)(s_H + (((size_t)(w * 4 + nt)) * 64 + lp) * 8 + jo) = hv;
            }
        }
    }
    BAR();

    // ---------------- Phase C: out = relu(W2 @ h + b2), K=256 --------------
    f32x4 oacc[4];
    #pragma unroll
    for (int nt = 0; nt < 4; ++nt)
        oacc[nt] = (f32x4){0.f, 0.f, 0.f, 0.f};

    #pragma unroll
    for (int oc = 0; oc < 8; ++oc) {
        if (oc + 1 < 8) loadW2(oc + 1, afP2[(oc + 1) & 1]);
        __builtin_amdgcn_s_setprio(1);
        #pragma unroll
        for (int nt = 0; nt < 4; ++nt) {
            const f16x8 bf = *(const f16x8*)(s_H + (((size_t)(oc * 4 + nt)) * 64 + L) * 8);
            oacc[nt] = __builtin_amdgcn_mfma_f32_16x16x32_f16(afP2[oc & 1], bf, oacc[nt], 0, 0, 0);
        }
        __builtin_amdgcn_s_setprio(0);
    }

    // epilogue: bias + relu + store (o = w*16 + quad*4 + j)
    {
        const f32x4 bb2 = *(const f32x4*)(b2v + w * 16 + quad * 4);
        #pragma unroll
        for (int nt = 0; nt < 4; ++nt) {
            float* op = out + ((size_t)b * H2c + w * 16 + quad * 4) * NPTS
                            + n0 + nt * 16 + l16;
            #pragma unroll
            for (int j = 0; j < 4; ++j)
                op[(size_t)j * NPTS] = fmaxf(oacc[nt][j] + bb2[j], 0.f);
        }
    }
}

extern "C" void kernel_launch(void* const* d_in, const int* in_sizes, int n_in,
                              void* d_out, int out_size, void* d_ws, size_t ws_size,
                              hipStream_t stream) {
    (void)in_sizes; (void)n_in; (void)out_size;
    const float* xyz1 = (const float*)d_in[0];
    const float* xyz2 = (const float*)d_in[1];
    const float* p1   = (const float*)d_in[2];
    const float* p2   = (const float*)d_in[3];
    const float* W1   = (const float*)d_in[4];
    const float* b1   = (const float*)d_in[5];
    const float* W2   = (const float*)d_in[6];
    const float* b2   = (const float*)d_in[7];
    float* out = (float*)d_out;

    dim3 grid(BBATCH * (NPTS / TN));   // 1024 blocks @ 3 resident/CU
    dim3 block(512);
    if (ws_size >= (size_t)WS_F16_TOTAL * 2) {
        _Float16* ws = (_Float16*)d_ws;
        const int nswz = NFRAG_P2 + NFRAG_W1 + NFRAG_W2;   // 540672 = 2112 * 256
        cvt_swz<<<dim3(nswz / 256), dim3(256), 0, stream>>>(p2, W1, W2, ws);
        fp_mfma14<true><<<grid, block, 0, stream>>>(xyz1, xyz2, p1, p2, W1, b1, W2, b2,
                                                    ws + WS_P2S, ws + WS_W1S, ws + WS_W2S, out);
    } else {
        fp_mfma14<false><<<grid, block, 0, stream>>>(xyz1, xyz2, p1, p2, W1, b1, W2, b2,
                                                     nullptr, nullptr, nullptr, out);
    }
}